// Round 5
// baseline (287.632 us; speedup 1.0000x reference)
//
#include <hip/hip_runtime.h>
#include <hip/hip_bf16.h>

#define T_DIM 1024
#define B_DIM 8
#define D_DIM 2048
#define E_DIM 6144   // 3*D
#define N_ROWS 8192  // T*B
#define K_DIM 2048
#define LN_EPS 1e-5f

#define S2  128   // scan chunks
#define CH2 8     // T per chunk
#define BD (B_DIM * D_DIM)  // 16384

typedef short bf16x8 __attribute__((ext_vector_type(8)));
typedef float f32x4 __attribute__((ext_vector_type(4)));
typedef float f32x16 __attribute__((ext_vector_type(16)));

__device__ __forceinline__ unsigned short f2bf(float f) {
  unsigned u = __float_as_uint(f);
  u += 0x7fffu + ((u >> 16) & 1u);  // round-to-nearest-even
  return (unsigned short)(u >> 16);
}
__device__ __forceinline__ float bf2f(unsigned short h) {
  return __uint_as_float(((unsigned)h) << 16);
}
__device__ __forceinline__ float fast_sigmoid(float x) {
  return __builtin_amdgcn_rcpf(1.f + __expf(-x));
}
__device__ __forceinline__ float fast_tanh(float x) {
  return 1.f - 2.f * __builtin_amdgcn_rcpf(__expf(2.f * x) + 1.f);
}

// ---------------- f32 -> bf16 conversion (vectorized) ----------------
__global__ __launch_bounds__(256) void cvt_kernel(const float* __restrict__ src,
                                                  unsigned short* __restrict__ dst,
                                                  int n4) {
  int i = blockIdx.x * 256 + threadIdx.x;
  if (i < n4) {
    float4 v = reinterpret_cast<const float4*>(src)[i];
    ushort4 o;
    o.x = f2bf(v.x); o.y = f2bf(v.y); o.z = f2bf(v.z); o.w = f2bf(v.w);
    reinterpret_cast<ushort4*>(dst)[i] = o;
  }
}

// ============ 256x256 bf16 32x32x16 MFMA GEMM, race-free phases ============
// C[N_ROWS,E] = A[N_ROWS,K] * Bw[E,K]^T, all bf16, f32 accumulate.
// 512 threads = 8 waves (2M x 4N). BK=64. LDS = 2 buffers x (A 32KB + B 32KB).
// LDS half-tile: [128 rows][128B] with swizzle byte^=((row&7)<<4); staged
// linear-dest with inverse-swizzled global source (verified mapping, R4).
//
// R5: fixes R2..R4's latent LDS write-after-read race. Rule: a region write
// must be >=2 phase barriers after the region's last read-ISSUE (the reader's
// data-dep wait lands one phase later; only the following barrier publishes
// it). Phase plan (8 MFMAs each = acc quadrant x 2 ks-steps, 4 indep chains):
//   ph0: MM acc[.][0] ks01 (hoisted); read a[0-3][2-3]+b[0][2-3] (buf)
//   ph1: MM acc[.][0] ks23; read b[1][0-1]; STAGE (j+1,h2/h3)->nbuf
//   ph2: MM acc[.][1] ks01; read b[1][2-3]; STAGE (j+2,h0)->buf
//   ph3: STAGE (j+2,h1)->buf; vmcnt(4); barrier;
//        hoist a[0-3][0-1]+b[0][0-1] (nbuf); MM acc[.][1] ks23
// Region audit (all satisfy q+2): buf-A last read ph0 -> writes ph2/ph3;
// buf-B last read ph2 -> writes next-iter ph1; nbuf-B last read ph3 (hoist)
// -> writes next-iter ph1; nbuf-A last read ph3 -> writes next-iter ph2.
#define NT2 32  // K_DIM / 64

__global__ __launch_bounds__(512, 2) void gemm8_kernel(
    const unsigned short* __restrict__ A,
    const unsigned short* __restrict__ Bw,
    unsigned short* __restrict__ C) {
  extern __shared__ __align__(16) char smem[];
  const int tid  = threadIdx.x;
  const int lane = tid & 63;
  const int wave = tid >> 6;
  const int wm = wave >> 2;   // 0..1  (M half)
  const int wn = wave & 3;    // 0..3  (N quarter)

  // XCD-aware mapping: concurrent set per XCD = 4 M-tiles x 8 N-tiles.
  const int bid = blockIdx.x;
  const int tileM = ((bid & 7) * 4 + ((bid >> 3) & 3)) * 256;
  const int tileN = (bid >> 5) * 256;

  // staging: dest byte p = wave*2048 + L*1024 + lane*16 (linear, 16KB half).
  // LDS physical p holds logical q with col = (p&127)^((row&7)<<4), row=p>>7.
  const int p0i = wave * 2048 + lane * 16;
  const int p1i = p0i + 1024;
  const int r0i = p0i >> 7;
  const int r1i = p1i >> 7;
  const int go0 = r0i * 4096 + ((p0i & 127) ^ ((r0i & 7) << 4));
  const int go1 = r1i * 4096 + ((p1i & 127) ^ ((r1i & 7) << 4));
  const char* Ab = (const char*)A + (size_t)tileM * 4096;
  const char* Bb = (const char*)Bw + (size_t)tileN * 4096;

#define STAGE(kt, h, bufOff)                                                 \
  {                                                                          \
    const char* gs_ = ((h) < 2 ? Ab : Bb) +                                  \
                      (size_t)(((h) & 1) * 128) * 4096 + (size_t)(kt) * 128; \
    char* ds_ = smem + (bufOff) + (h) * 16384 + wave * 2048;                 \
    __builtin_amdgcn_global_load_lds(                                        \
        (const __attribute__((address_space(1))) void*)(gs_ + go0),          \
        (__attribute__((address_space(3))) void*)ds_, 16, 0, 0);             \
    __builtin_amdgcn_global_load_lds(                                        \
        (const __attribute__((address_space(1))) void*)(gs_ + go1),          \
        (__attribute__((address_space(3))) void*)(ds_ + 1024), 16, 0, 0);    \
  }

  // fragment reads: lane holds row/col = lane&31, k = (lane>>5)*8 + j.
  // byte = half + blk*4096 + (lane&31)*128 + cell'*16,
  // cell = ks*2 + (lane>>5), cell' = cell ^ (lane&7).
  const int rlo  = (lane & 31) * 128;
  const int kg   = lane >> 5;       // k-group
  const int sw   = lane & 7;        // swizzle bits
  const int aOff = wm * 16384;
  const int bOff = 32768 + (wn >> 1) * 16384 + (wn & 1) * 8192;

#define CELL(ks) ((((((ks) << 1) | kg) ^ sw)) << 4)
#define RDA(mi, ks, bufOff)                                                    \
  a[mi][ks] = *reinterpret_cast<const bf16x8*>(                                \
      smem + (bufOff) + aOff + (mi) * 4096 + rlo + CELL(ks));
#define RDB(ni, ks, bufOff)                                                    \
  b[ni][ks] = *reinterpret_cast<const bf16x8*>(                                \
      smem + (bufOff) + bOff + (ni) * 4096 + rlo + CELL(ks));
#define MM1(mi, ni, ks)                                                        \
  acc[mi][ni] = __builtin_amdgcn_mfma_f32_32x32x16_bf16(a[mi][ks], b[ni][ks],  \
                                                        acc[mi][ni], 0, 0, 0);
#define MMQ(ni, ka, kb)                                                        \
  MM1(0, ni, ka) MM1(1, ni, ka) MM1(2, ni, ka) MM1(3, ni, ka)                  \
  MM1(0, ni, kb) MM1(1, ni, kb) MM1(2, ni, kb) MM1(3, ni, kb)

  bf16x8 a[4][4], b[2][4];
  f32x16 acc[4][2] = {};

  // prologue: stage tile0 fully + tile1 h0,h1; drain tile0 (8 oldest of 12);
  // hoist ks0-1 A frags + b[0] ks0-1 of tile0.
  STAGE(0, 0, 0); STAGE(0, 1, 0); STAGE(0, 2, 0); STAGE(0, 3, 0);
  STAGE(1, 0, 65536); STAGE(1, 1, 65536);
  asm volatile("s_waitcnt vmcnt(4)" ::: "memory");
  __builtin_amdgcn_s_barrier();
  RDA(0, 0, 0); RDA(1, 0, 0); RDA(2, 0, 0); RDA(3, 0, 0);
  RDA(0, 1, 0); RDA(1, 1, 0); RDA(2, 1, 0); RDA(3, 1, 0);
  RDB(0, 0, 0); RDB(0, 1, 0);

  for (int j = 0; j < NT2; ++j) {
    const int buf  = (j & 1) << 16;
    const int nbuf = buf ^ 65536;
    // ---- ph0: MM acc[.][0] ks01; read a[.][2-3], b[0][2-3] from buf ----
    __builtin_amdgcn_s_setprio(1);
    RDA(0, 2, buf); RDA(1, 2, buf); RDA(2, 2, buf); RDA(3, 2, buf);
    RDA(0, 3, buf); RDA(1, 3, buf); RDA(2, 3, buf); RDA(3, 3, buf);
    RDB(0, 2, buf); RDB(0, 3, buf);
    MMQ(0, 0, 1);
    __builtin_amdgcn_s_setprio(0);
    __builtin_amdgcn_s_barrier();
    // ---- ph1: MM acc[.][0] ks23; read b[1][0-1]; stage (j+1,h2/h3)->nbuf ----
    __builtin_amdgcn_s_setprio(1);
    if (j < NT2 - 1) { STAGE(j + 1, 2, nbuf); STAGE(j + 1, 3, nbuf); }
    RDB(1, 0, buf); RDB(1, 1, buf);
    MMQ(0, 2, 3);
    __builtin_amdgcn_s_setprio(0);
    __builtin_amdgcn_s_barrier();
    // ---- ph2: MM acc[.][1] ks01; read b[1][2-3]; stage (j+2,h0)->buf ----
    __builtin_amdgcn_s_setprio(1);
    if (j < NT2 - 2) STAGE(j + 2, 0, buf);
    RDB(1, 2, buf); RDB(1, 3, buf);
    MMQ(1, 0, 1);
    __builtin_amdgcn_s_setprio(0);
    __builtin_amdgcn_s_barrier();
    // ---- ph3: stage (j+2,h1)->buf; drain tile j+1; hoist next ks01 (nbuf);
    //           MM acc[.][1] ks23 ----
    if (j < NT2 - 2) {
      STAGE(j + 2, 1, buf);
      asm volatile("s_waitcnt vmcnt(4)" ::: "memory");   // completes tile j+1
    } else if (j == NT2 - 2) {
      asm volatile("s_waitcnt vmcnt(0)" ::: "memory");
    }
    __builtin_amdgcn_s_barrier();
    __builtin_amdgcn_s_setprio(1);
    if (j < NT2 - 1) {
      RDA(0, 0, nbuf); RDA(1, 0, nbuf); RDA(2, 0, nbuf); RDA(3, 0, nbuf);
      RDA(0, 1, nbuf); RDA(1, 1, nbuf); RDA(2, 1, nbuf); RDA(3, 1, nbuf);
      RDB(0, 0, nbuf); RDB(0, 1, nbuf);
    }
    MMQ(1, 2, 3);
    __builtin_amdgcn_s_setprio(0);
    __builtin_amdgcn_s_barrier();
  }

  // epilogue: 32x32 C/D layout col=lane&31, row=(reg&3)+8*(reg>>2)+4*(lane>>5)
  const int ccol = lane & 31;
  const int rb2  = (lane >> 5) * 4;
#pragma unroll
  for (int mi = 0; mi < 4; ++mi) {
#pragma unroll
    for (int ni = 0; ni < 2; ++ni) {
#pragma unroll
      for (int reg = 0; reg < 16; ++reg) {
        int row = tileM + wm * 128 + mi * 32 + (reg & 3) + ((reg >> 2) << 3) + rb2;
        int col = tileN + wn * 64 + ni * 32 + ccol;
        C[(size_t)row * E_DIM + col] = f2bf(acc[mi][ni][reg]);
      }
    }
  }
#undef STAGE
#undef CELL
#undef RDA
#undef RDB
#undef MM1
#undef MMQ
}

// ---------------- blocked parallel scan ----------------
// P1: per (b,d,chunk) affine composition over CH2 steps
__global__ __launch_bounds__(256) void scan_p1_kernel(
    const unsigned short* __restrict__ ufr,
    float* __restrict__ Aout, float* __restrict__ Bout) {
  const int idx = blockIdx.x * 256 + threadIdx.x;  // (b,d)
  const int s = blockIdx.y;
  const int b = idx >> 11;
  const int d = idx & 2047;
  const unsigned short* up =
      ufr + ((size_t)(s * CH2) * B_DIM + b) * E_DIM + d;
  float Aacc = 1.f, Bacc = 0.f;
#pragma unroll
  for (int it = 0; it < CH2; ++it) {
    float u  = bf2f(up[0]);
    float fl = bf2f(up[D_DIM]);
    float f = fast_sigmoid(fl);
    Aacc *= f;
    Bacc = f * Bacc + (1.f - f) * u;
    up += (size_t)B_DIM * E_DIM;
  }
  Aout[(size_t)s * BD + idx] = Aacc;
  Bout[(size_t)s * BD + idx] = Bacc;
}

// P2: compose chunk boundaries sequentially
__global__ __launch_bounds__(256) void scan_p2_kernel(
    const float* __restrict__ c0,
    const float* __restrict__ Ain, const float* __restrict__ Bin,
    float* __restrict__ cs, float* __restrict__ cT) {
  const int idx = blockIdx.x * 256 + threadIdx.x;
  float c = c0[idx];
  for (int s = 0; s < S2; ++s) {
    cs[(size_t)s * BD + idx] = c;
    c = Ain[(size_t)s * BD + idx] * c + Bin[(size_t)s * BD + idx];
  }
  cT[idx] = c;
}

// P3 fused with GELU+LN: block = (b, chunk); 256 threads cover all D=2048.
// Re-runs CH2 steps from the chunk start state, then per-t block-LN, writes out.
__global__ __launch_bounds__(256) void scan_p3ln_kernel(
    const float* __restrict__ x,
    const unsigned short* __restrict__ ufr,
    const float* __restrict__ cs,
    const float* __restrict__ gamma,
    const float* __restrict__ beta,
    float* __restrict__ out) {
  const int b = blockIdx.x & (B_DIM - 1);
  const int s = blockIdx.x >> 3;
  const int tid = threadIdx.x;
  const int lane = tid & 63;
  const int wave = tid >> 6;
  const int d0 = tid * 8;
  __shared__ float red[8];

  float c[8];
  {
    const float* csp = cs + (size_t)s * BD + b * D_DIM + d0;
    float4 v0 = *(const float4*)csp;
    float4 v1 = *(const float4*)(csp + 4);
    c[0]=v0.x; c[1]=v0.y; c[2]=v0.z; c[3]=v0.w;
    c[4]=v1.x; c[5]=v1.y; c[6]=v1.z; c[7]=v1.w;
  }
  float gam[8], bet[8];
  {
    float4 g0 = *(const float4*)(gamma + d0);
    float4 g1 = *(const float4*)(gamma + d0 + 4);
    float4 b0 = *(const float4*)(beta + d0);
    float4 b1 = *(const float4*)(beta + d0 + 4);
    gam[0]=g0.x; gam[1]=g0.y; gam[2]=g0.z; gam[3]=g0.w;
    gam[4]=g1.x; gam[5]=g1.y; gam[6]=g1.z; gam[7]=g1.w;
    bet[0]=b0.x; bet[1]=b0.y; bet[2]=b0.z; bet[3]=b0.w;
    bet[4]=b1.x; bet[5]=b1.y; bet[6]=b1.z; bet[7]=b1.w;
  }

  for (int it = 0; it < CH2; ++it) {
    const size_t rowo = (size_t)(s * CH2 + it) * B_DIM + b;
    const unsigned short* up = ufr + rowo * E_DIM + d0;
    const float* xp = x + rowo * D_DIM + d0;
    ushort4 uv0 = *(const ushort4*)up;
    ushort4 uv1 = *(const ushort4*)(up + 4);
    ushort4 fv0 = *(const ushort4*)(up + D_DIM);
    ushort4 fv1 = *(const ushort4*)(up + D_DIM + 4);
    ushort4 rv0 = *(const ushort4*)(up + 2 * D_DIM);
    ushort4 rv1 = *(const ushort4*)(up + 2 * D_DIM + 4);
    float4 xv0 = *(const float4*)xp;
    float4 xv1 = *(const float4*)(xp + 4);
    unsigned short uu[8] = {uv0.x, uv0.y, uv0.z, uv0.w, uv1.x, uv1.y, uv1.z, uv1.w};
    unsigned short ff[8] = {fv0.x, fv0.y, fv0.z, fv0.w, fv1.x, fv1.y, fv1.z, fv1.w};
    unsigned short rr[8] = {rv0.x, rv0.y, rv0.z, rv0.w, rv1.x, rv1.y, rv1.z, rv1.w};
    float xx[8] = {xv0.x, xv0.y, xv0.z, xv0.w, xv1.x, xv1.y, xv1.z, xv1.w};

    float g[8];
    float s1 = 0.f, sq = 0.f;
#pragma unroll
    for (int jj = 0; jj < 8; ++jj) {
      float f = fast_sigmoid(bf2f(ff[jj]));
      float r = fast_sigmoid(bf2f(rr[jj]));
      c[jj] = f * c[jj] + (1.f - f) * bf2f(uu[jj]);
      float h = r * fast_tanh(c[jj]) + (1.f - r) * xx[jj];
      float gg = 0.5f * h * (1.f + erff(h * 0.70710678118654752f));
      g[jj] = gg;
      s1 += gg;
      sq += gg * gg;
    }
#pragma unroll
    for (int off = 32; off; off >>= 1) {
      s1 += __shfl_xor(s1, off);
      sq += __shfl_xor(sq, off);
    }
    if (lane == 0) { red[wave] = s1; red[4 + wave] = sq; }
    __syncthreads();
    float S1 = red[0] + red[1] + red[2] + red[3];
    float Sq = red[4] + red[5] + red[6] + red[7];
    __syncthreads();  // red reused next iteration
    float mean = S1 * (1.f / D_DIM);
    float var  = Sq * (1.f / D_DIM) - mean * mean;
    float inv = rsqrtf(var + LN_EPS);

    float* op = out + rowo * D_DIM + d0;
    float4 o0 = {(g[0] - mean) * inv * gam[0] + bet[0],
                 (g[1] - mean) * inv * gam[1] + bet[1],
                 (g[2] - mean) * inv * gam[2] + bet[2],
                 (g[3] - mean) * inv * gam[3] + bet[3]};
    float4 o1 = {(g[4] - mean) * inv * gam[4] + bet[4],
                 (g[5] - mean) * inv * gam[5] + bet[5],
                 (g[6] - mean) * inv * gam[6] + bet[6],
                 (g[7] - mean) * inv * gam[7] + bet[7]};
    *(float4*)op = o0;
    *(float4*)(op + 4) = o1;
  }
}

extern "C" void kernel_launch(void* const* d_in, const int* in_sizes, int n_in,
                              void* d_out, int out_size, void* d_ws, size_t ws_size,
                              hipStream_t stream) {
  const float* x     = (const float*)d_in[0];
  const float* c0    = (const float*)d_in[1];
  const float* W     = (const float*)d_in[2];
  const float* gamma = (const float*)d_in[3];
  const float* beta  = (const float*)d_in[4];
  float* out = (float*)d_out;
  float* cT  = out + (size_t)N_ROWS * D_DIM;

  unsigned short* ufr = (unsigned short*)d_ws;                 // [N_ROWS][E] bf16
  unsigned short* xb  = ufr + (size_t)N_ROWS * E_DIM;          // [N_ROWS][K] bf16
  unsigned short* wb  = xb + (size_t)N_ROWS * K_DIM;           // [E][K] bf16

  // scan scratch reuses xb region (dead after gemm): 3 * S2*BD*4 = 25.2MB < 33.5MB
  float* Abuf = (float*)xb;
  float* Bbuf = Abuf + (size_t)S2 * BD;
  float* csb  = Bbuf + (size_t)S2 * BD;

  int nx4 = N_ROWS * K_DIM / 4;
  int nw4 = E_DIM * K_DIM / 4;
  cvt_kernel<<<(nx4 + 255) / 256, 256, 0, stream>>>(x, xb, nx4);
  cvt_kernel<<<(nw4 + 255) / 256, 256, 0, stream>>>(W, wb, nw4);

  (void)hipFuncSetAttribute((const void*)gemm8_kernel,
                            hipFuncAttributeMaxDynamicSharedMemorySize, 131072);
  gemm8_kernel<<<768, 512, 131072, stream>>>(xb, wb, ufr);

  dim3 sg(BD / 256, S2);
  scan_p1_kernel<<<sg, 256, 0, stream>>>(ufr, Abuf, Bbuf);
  scan_p2_kernel<<<BD / 256, 256, 0, stream>>>(c0, Abuf, Bbuf, csb, cT);
  scan_p3ln_kernel<<<B_DIM * S2, 256, 0, stream>>>(x, ufr, csb, gamma, beta, out);
}

// Round 6
// 267.625 us; speedup vs baseline: 1.0748x; 1.0748x over previous
//
#include <hip/hip_runtime.h>
#include <hip/hip_bf16.h>

#define T_DIM 1024
#define B_DIM 8
#define D_DIM 2048
#define E_DIM 6144   // 3*D
#define N_ROWS 8192  // T*B
#define K_DIM 2048
#define LN_EPS 1e-5f

#define S2  128   // scan chunks
#define CH2 8     // T per chunk
#define BD (B_DIM * D_DIM)  // 16384

typedef short bf16x8 __attribute__((ext_vector_type(8)));
typedef float f32x4 __attribute__((ext_vector_type(4)));

__device__ __forceinline__ unsigned short f2bf(float f) {
  unsigned u = __float_as_uint(f);
  u += 0x7fffu + ((u >> 16) & 1u);  // round-to-nearest-even
  return (unsigned short)(u >> 16);
}
__device__ __forceinline__ float bf2f(unsigned short h) {
  return __uint_as_float(((unsigned)h) << 16);
}
__device__ __forceinline__ float fast_sigmoid(float x) {
  return __builtin_amdgcn_rcpf(1.f + __expf(-x));
}
__device__ __forceinline__ float fast_tanh(float x) {
  return 1.f - 2.f * __builtin_amdgcn_rcpf(__expf(2.f * x) + 1.f);
}

// ------- f32 -> bf16 conversion (vectorized, x and W in one launch) -------
__global__ __launch_bounds__(256) void cvt2_kernel(
    const float* __restrict__ src0, unsigned short* __restrict__ dst0, int n0,
    const float* __restrict__ src1, unsigned short* __restrict__ dst1, int n1) {
  int i = blockIdx.x * 256 + threadIdx.x;
  const float* s;
  unsigned short* d;
  if (i < n0) {
    s = src0; d = dst0;
  } else {
    i -= n0;
    if (i >= n1) return;
    s = src1; d = dst1;
  }
  float4 v = reinterpret_cast<const float4*>(s)[i];
  ushort4 o;
  o.x = f2bf(v.x); o.y = f2bf(v.y); o.z = f2bf(v.z); o.w = f2bf(v.w);
  reinterpret_cast<ushort4*>(d)[i] = o;
}

// ============ 256x256 8-phase bf16 MFMA GEMM (T1+T2+T3/T4+T5) ============
// C[N_ROWS,E] = A[N_ROWS,K] * Bw[E,K]^T, all bf16, f32 accumulate.
// 512 threads = 8 waves (2M x 4N). BK=64. LDS = 2 buffers x (A 32KB + B 32KB).
// Half-tile layout: 2 k-panels (ks=0/1) of [128 rows][32 bf16] (64B rows),
// swizzled byte^=((b>>9)&1)<<5; staged linear-dest with inverse-swz source.
//
// R2 (verified 175.4us, 0 bank conflicts): ds_reads software-pipelined ONE
// PHASE AHEAD — each phase's fragment reads are issued inside the previous
// phase's MFMA region, so the phase-top lgkmcnt(0) is ~free. Phase 2/3 MFMA
// quadrants swapped vs r0 so phase 3 consumes a[4-7]/b[2-3], freeing
// a[0-3]/b[0-1] for the next iteration's hoisted reads (which sit strictly
// after phase 3's vmcnt(4)+barrier = entire next tile drained).
// NOTE (R4 lesson): the hoisted reads are 1 barrier ahead of the next
// buf-write; this is the verified-on-hardware R2 schedule — do not reorder
// reads/stages within phases without re-auditing the write-after-read rule.
#define NT2 32  // K_DIM / 64

__global__ __launch_bounds__(512, 2) void gemm8_kernel(
    const unsigned short* __restrict__ A,
    const unsigned short* __restrict__ Bw,
    unsigned short* __restrict__ C) {
  extern __shared__ __align__(16) char smem[];
  const int tid  = threadIdx.x;
  const int lane = tid & 63;
  const int wave = tid >> 6;
  const int wm = wave >> 2;   // 0..1  (M half)
  const int wn = wave & 3;    // 0..3  (N quarter)

  // XCD-aware mapping: concurrent set per XCD = 4 M-tiles x 8 N-tiles.
  // bid&7 -> XCD; M-tile = xcd*4 + (bid>>3)&3; N-tile = bid>>5. Bijective on 768.
  const int bid = blockIdx.x;
  const int tileM = ((bid & 7) * 4 + ((bid >> 3) & 3)) * 256;
  const int tileN = (bid >> 5) * 256;

  // staging: dest byte p = wave*2048 + L*1024 + lane*16 (linear);
  // logical q = p ^ ((p>>9)&1)<<5 -> (panel=q>>13, row=(q>>6)&127, off=q&63)
  const int p0i = wave * 2048 + lane * 16;
  const int p1i = p0i + 1024;
  const int q0i = p0i ^ (((p0i >> 9) & 1) << 5);
  const int q1i = p1i ^ (((p1i >> 9) & 1) << 5);
  const int go0 = ((q0i >> 6) & 127) * 4096 + ((q0i >> 13) << 6) + (q0i & 63);
  const int go1 = ((q1i >> 6) & 127) * 4096 + ((q1i >> 13) << 6) + (q1i & 63);
  const char* Ab = (const char*)A + (size_t)tileM * 4096;
  const char* Bb = (const char*)Bw + (size_t)tileN * 4096;

#define STAGE(kt, h, bufOff)                                                 \
  {                                                                          \
    const char* gs_ = ((h) < 2 ? Ab : Bb) +                                  \
                      (size_t)(((h) & 1) * 128) * 4096 + (size_t)(kt) * 128; \
    char* ds_ = smem + (bufOff) + (h) * 16384 + wave * 2048;                 \
    __builtin_amdgcn_global_load_lds(                                        \
        (const __attribute__((address_space(1))) void*)(gs_ + go0),          \
        (__attribute__((address_space(3))) void*)ds_, 16, 0, 0);             \
    __builtin_amdgcn_global_load_lds(                                        \
        (const __attribute__((address_space(1))) void*)(gs_ + go1),          \
        (__attribute__((address_space(3))) void*)(ds_ + 1024), 16, 0, 0);    \
  }

  // ds_read fragment bases (swizzled)
  const int xbit = ((lane >> 3) & 1) << 5;  // row bit3 -> flip byte bit5
  const int aBase = wm * 16384 +
                    (((lane & 15) * 64 + (lane >> 4) * 16) ^ xbit);
  const int bBase = 32768 + (wn >> 1) * 16384 +
                    ((((wn & 1) * 64 + (lane & 15)) * 64 + (lane >> 4) * 16) ^ xbit);

#define RDA(m, bufOff)                                                          \
  a[m][0] = *reinterpret_cast<const bf16x8*>(smem + (bufOff) + aBase + (m) * 1024);        \
  a[m][1] = *reinterpret_cast<const bf16x8*>(smem + (bufOff) + aBase + (m) * 1024 + 8192);
#define RDB(n, bufOff)                                                          \
  b[n][0] = *reinterpret_cast<const bf16x8*>(smem + (bufOff) + bBase + (n) * 1024);        \
  b[n][1] = *reinterpret_cast<const bf16x8*>(smem + (bufOff) + bBase + (n) * 1024 + 8192);
#define MM(m, n)                                                                \
  acc[m][n] = __builtin_amdgcn_mfma_f32_16x16x32_bf16(a[m][0], b[n][0], acc[m][n], 0, 0, 0); \
  acc[m][n] = __builtin_amdgcn_mfma_f32_16x16x32_bf16(a[m][1], b[n][1], acc[m][n], 0, 0, 0);

  bf16x8 a[8][2], b[4][2];
  f32x4 acc[8][4] = {};

  // prologue: stage tile0 fully + tile1 h0,h1; drain tile0 (8 oldest of 12);
  // then pre-issue phase-0's fragment reads (a[0-3], b[0-1] of tile 0).
  STAGE(0, 0, 0); STAGE(0, 1, 0); STAGE(0, 2, 0); STAGE(0, 3, 0);
  STAGE(1, 0, 65536); STAGE(1, 1, 65536);
  asm volatile("s_waitcnt vmcnt(4)" ::: "memory");
  __builtin_amdgcn_s_barrier();
  RDA(0, 0); RDA(1, 0); RDA(2, 0); RDA(3, 0);
  RDB(0, 0); RDB(1, 0);

  for (int j = 0; j < NT2; ++j) {
    const int buf  = (j & 1) << 16;
    const int nbuf = buf ^ 65536;
    // ---- phase 0: MFMA(0-3 x 0-1); prefetch a[4-7]; stage (j+1,h2) ----
    asm volatile("s_waitcnt lgkmcnt(0)" ::: "memory");
    __builtin_amdgcn_s_setprio(1);
    if (j < NT2 - 1) STAGE(j + 1, 2, nbuf);
    RDA(4, buf); RDA(5, buf); RDA(6, buf); RDA(7, buf);
    MM(0, 0); MM(0, 1); MM(1, 0); MM(1, 1);
    MM(2, 0); MM(2, 1); MM(3, 0); MM(3, 1);
    __builtin_amdgcn_s_setprio(0);
    __builtin_amdgcn_s_barrier();
    // ---- phase 1: MFMA(4-7 x 0-1); prefetch b[2-3]; stage (j+1,h3) ----
    asm volatile("s_waitcnt lgkmcnt(0)" ::: "memory");
    __builtin_amdgcn_s_setprio(1);
    if (j < NT2 - 1) STAGE(j + 1, 3, nbuf);
    RDB(2, buf); RDB(3, buf);
    MM(4, 0); MM(4, 1); MM(5, 0); MM(5, 1);
    MM(6, 0); MM(6, 1); MM(7, 0); MM(7, 1);
    __builtin_amdgcn_s_setprio(0);
    __builtin_amdgcn_s_barrier();
    // ---- phase 2: MFMA(0-3 x 2-3); stage (j+2,h0)->buf ----
    // (buf A-reads all completed by ph1-top lgkm across waves + ph1 barrier)
    asm volatile("s_waitcnt lgkmcnt(0)" ::: "memory");
    __builtin_amdgcn_s_setprio(1);
    if (j < NT2 - 2) STAGE(j + 2, 0, buf);
    MM(0, 2); MM(0, 3); MM(1, 2); MM(1, 3);
    MM(2, 2); MM(2, 3); MM(3, 2); MM(3, 3);
    __builtin_amdgcn_s_setprio(0);
    __builtin_amdgcn_s_barrier();
    // ---- phase 3: stage (j+2,h1)->buf; drain tile j+1; MFMA(4-7 x 2-3);
    //      hoist next iteration's phase-0 reads (a[0-3],b[0-1] from nbuf) ----
    if (j < NT2 - 2) {
      STAGE(j + 2, 1, buf);
      asm volatile("s_waitcnt vmcnt(4)" ::: "memory");   // completes tile j+1
    } else if (j == NT2 - 2) {
      asm volatile("s_waitcnt vmcnt(0)" ::: "memory");
    }
    __builtin_amdgcn_s_barrier();
    __builtin_amdgcn_s_setprio(1);
    RDA(0, nbuf); RDA(1, nbuf); RDA(2, nbuf); RDA(3, nbuf);
    RDB(0, nbuf); RDB(1, nbuf);
    MM(4, 2); MM(4, 3); MM(5, 2); MM(5, 3);
    MM(6, 2); MM(6, 3); MM(7, 2); MM(7, 3);
    __builtin_amdgcn_s_setprio(0);
    __builtin_amdgcn_s_barrier();
  }

  // epilogue: C/D layout col=lane&15, row=(lane>>4)*4+jj
  const int crow = (lane >> 4) * 4;
  const int ccol = lane & 15;
#pragma unroll
  for (int m = 0; m < 8; ++m) {
#pragma unroll
    for (int n = 0; n < 4; ++n) {
#pragma unroll
      for (int jj = 0; jj < 4; ++jj) {
        int row = tileM + wm * 128 + m * 16 + crow + jj;
        int col = tileN + wn * 64 + n * 16 + ccol;
        C[(size_t)row * E_DIM + col] = f2bf(acc[m][n][jj]);
      }
    }
  }
#undef STAGE
#undef RDA
#undef RDB
#undef MM
}

// ---------------- blocked parallel scan ----------------
// P1: per (b,d,chunk) affine composition over CH2 steps
__global__ __launch_bounds__(256) void scan_p1_kernel(
    const unsigned short* __restrict__ ufr,
    float* __restrict__ Aout, float* __restrict__ Bout) {
  const int idx = blockIdx.x * 256 + threadIdx.x;  // (b,d)
  const int s = blockIdx.y;
  const int b = idx >> 11;
  const int d = idx & 2047;
  const unsigned short* up =
      ufr + ((size_t)(s * CH2) * B_DIM + b) * E_DIM + d;
  float Aacc = 1.f, Bacc = 0.f;
#pragma unroll
  for (int it = 0; it < CH2; ++it) {
    float u  = bf2f(up[0]);
    float fl = bf2f(up[D_DIM]);
    float f = fast_sigmoid(fl);
    Aacc *= f;
    Bacc = f * Bacc + (1.f - f) * u;
    up += (size_t)B_DIM * E_DIM;
  }
  Aout[(size_t)s * BD + idx] = Aacc;
  Bout[(size_t)s * BD + idx] = Bacc;
}

// P2: compose chunk boundaries sequentially
__global__ __launch_bounds__(256) void scan_p2_kernel(
    const float* __restrict__ c0,
    const float* __restrict__ Ain, const float* __restrict__ Bin,
    float* __restrict__ cs, float* __restrict__ cT) {
  const int idx = blockIdx.x * 256 + threadIdx.x;
  float c = c0[idx];
  for (int s = 0; s < S2; ++s) {
    cs[(size_t)s * BD + idx] = c;
    c = Ain[(size_t)s * BD + idx] * c + Bin[(size_t)s * BD + idx];
  }
  cT[idx] = c;
}

// P3 fused with GELU+LN: block = (b, chunk); 256 threads cover all D=2048.
// Re-runs CH2 steps from the chunk start state, then per-t block-LN, writes out.
// R6: reads x as bf16 (xb) — halves the x-read traffic of this BW-bound kernel.
__global__ __launch_bounds__(256) void scan_p3ln_kernel(
    const unsigned short* __restrict__ xb,
    const unsigned short* __restrict__ ufr,
    const float* __restrict__ cs,
    const float* __restrict__ gamma,
    const float* __restrict__ beta,
    float* __restrict__ out) {
  const int b = blockIdx.x & (B_DIM - 1);
  const int s = blockIdx.x >> 3;
  const int tid = threadIdx.x;
  const int lane = tid & 63;
  const int wave = tid >> 6;
  const int d0 = tid * 8;
  __shared__ float red[8];

  float c[8];
  {
    const float* csp = cs + (size_t)s * BD + b * D_DIM + d0;
    float4 v0 = *(const float4*)csp;
    float4 v1 = *(const float4*)(csp + 4);
    c[0]=v0.x; c[1]=v0.y; c[2]=v0.z; c[3]=v0.w;
    c[4]=v1.x; c[5]=v1.y; c[6]=v1.z; c[7]=v1.w;
  }
  float gam[8], bet[8];
  {
    float4 g0 = *(const float4*)(gamma + d0);
    float4 g1 = *(const float4*)(gamma + d0 + 4);
    float4 b0 = *(const float4*)(beta + d0);
    float4 b1 = *(const float4*)(beta + d0 + 4);
    gam[0]=g0.x; gam[1]=g0.y; gam[2]=g0.z; gam[3]=g0.w;
    gam[4]=g1.x; gam[5]=g1.y; gam[6]=g1.z; gam[7]=g1.w;
    bet[0]=b0.x; bet[1]=b0.y; bet[2]=b0.z; bet[3]=b0.w;
    bet[4]=b1.x; bet[5]=b1.y; bet[6]=b1.z; bet[7]=b1.w;
  }

  for (int it = 0; it < CH2; ++it) {
    const size_t rowo = (size_t)(s * CH2 + it) * B_DIM + b;
    const unsigned short* up = ufr + rowo * E_DIM + d0;
    const unsigned short* xp = xb + rowo * D_DIM + d0;
    ushort4 uv0 = *(const ushort4*)up;
    ushort4 uv1 = *(const ushort4*)(up + 4);
    ushort4 fv0 = *(const ushort4*)(up + D_DIM);
    ushort4 fv1 = *(const ushort4*)(up + D_DIM + 4);
    ushort4 rv0 = *(const ushort4*)(up + 2 * D_DIM);
    ushort4 rv1 = *(const ushort4*)(up + 2 * D_DIM + 4);
    ushort4 xv0 = *(const ushort4*)xp;
    ushort4 xv1 = *(const ushort4*)(xp + 4);
    unsigned short uu[8] = {uv0.x, uv0.y, uv0.z, uv0.w, uv1.x, uv1.y, uv1.z, uv1.w};
    unsigned short ff[8] = {fv0.x, fv0.y, fv0.z, fv0.w, fv1.x, fv1.y, fv1.z, fv1.w};
    unsigned short rr[8] = {rv0.x, rv0.y, rv0.z, rv0.w, rv1.x, rv1.y, rv1.z, rv1.w};
    unsigned short xx[8] = {xv0.x, xv0.y, xv0.z, xv0.w, xv1.x, xv1.y, xv1.z, xv1.w};

    float g[8];
    float s1 = 0.f, sq = 0.f;
#pragma unroll
    for (int jj = 0; jj < 8; ++jj) {
      float f = fast_sigmoid(bf2f(ff[jj]));
      float r = fast_sigmoid(bf2f(rr[jj]));
      c[jj] = f * c[jj] + (1.f - f) * bf2f(uu[jj]);
      float h = r * fast_tanh(c[jj]) + (1.f - r) * bf2f(xx[jj]);
      float gg = 0.5f * h * (1.f + erff(h * 0.70710678118654752f));
      g[jj] = gg;
      s1 += gg;
      sq += gg * gg;
    }
#pragma unroll
    for (int off = 32; off; off >>= 1) {
      s1 += __shfl_xor(s1, off);
      sq += __shfl_xor(sq, off);
    }
    if (lane == 0) { red[wave] = s1; red[4 + wave] = sq; }
    __syncthreads();
    float S1 = red[0] + red[1] + red[2] + red[3];
    float Sq = red[4] + red[5] + red[6] + red[7];
    __syncthreads();  // red reused next iteration
    float mean = S1 * (1.f / D_DIM);
    float var  = Sq * (1.f / D_DIM) - mean * mean;
    float inv = rsqrtf(var + LN_EPS);

    float* op = out + rowo * D_DIM + d0;
    float4 o0 = {(g[0] - mean) * inv * gam[0] + bet[0],
                 (g[1] - mean) * inv * gam[1] + bet[1],
                 (g[2] - mean) * inv * gam[2] + bet[2],
                 (g[3] - mean) * inv * gam[3] + bet[3]};
    float4 o1 = {(g[4] - mean) * inv * gam[4] + bet[4],
                 (g[5] - mean) * inv * gam[5] + bet[5],
                 (g[6] - mean) * inv * gam[6] + bet[6],
                 (g[7] - mean) * inv * gam[7] + bet[7]};
    *(float4*)op = o0;
    *(float4*)(op + 4) = o1;
  }
}

extern "C" void kernel_launch(void* const* d_in, const int* in_sizes, int n_in,
                              void* d_out, int out_size, void* d_ws, size_t ws_size,
                              hipStream_t stream) {
  const float* x     = (const float*)d_in[0];
  const float* c0    = (const float*)d_in[1];
  const float* W     = (const float*)d_in[2];
  const float* gamma = (const float*)d_in[3];
  const float* beta  = (const float*)d_in[4];
  float* out = (float*)d_out;
  float* cT  = out + (size_t)N_ROWS * D_DIM;

  unsigned short* ufr = (unsigned short*)d_ws;                 // [N_ROWS][E] bf16
  unsigned short* xb  = ufr + (size_t)N_ROWS * E_DIM;          // [N_ROWS][K] bf16
  unsigned short* wb  = xb + (size_t)N_ROWS * K_DIM;           // [E][K] bf16

  // scan scratch reuses wb region (dead after gemm; xb stays live for p3):
  // 3 * S2*BD*4 = 25,165,824 B == wb size exactly.
  float* Abuf = (float*)wb;
  float* Bbuf = Abuf + (size_t)S2 * BD;
  float* csb  = Bbuf + (size_t)S2 * BD;

  int nx4 = N_ROWS * K_DIM / 4;
  int nw4 = E_DIM * K_DIM / 4;
  cvt2_kernel<<<(nx4 + nw4 + 255) / 256, 256, 0, stream>>>(x, xb, nx4, W, wb, nw4);

  (void)hipFuncSetAttribute((const void*)gemm8_kernel,
                            hipFuncAttributeMaxDynamicSharedMemorySize, 131072);
  gemm8_kernel<<<768, 512, 131072, stream>>>(xb, wb, ufr);

  dim3 sg(BD / 256, S2);
  scan_p1_kernel<<<sg, 256, 0, stream>>>(ufr, Abuf, Bbuf);
  scan_p2_kernel<<<BD / 256, 256, 0, stream>>>(c0, Abuf, Bbuf, csb, cT);
  scan_p3ln_kernel<<<B_DIM * S2, 256, 0, stream>>>(xb, ufr, csb, gamma, beta, out);
}

// Round 7
// 266.885 us; speedup vs baseline: 1.0777x; 1.0028x over previous
//
#include <hip/hip_runtime.h>
#include <hip/hip_bf16.h>

#define T_DIM 1024
#define B_DIM 8
#define D_DIM 2048
#define E_DIM 6144   // 3*D
#define N_ROWS 8192  // T*B
#define K_DIM 2048
#define LN_EPS 1e-5f

#define S2  128   // scan chunks
#define CH2 8     // T per chunk
#define BD (B_DIM * D_DIM)  // 16384

typedef short bf16x8 __attribute__((ext_vector_type(8)));
typedef float f32x4 __attribute__((ext_vector_type(4)));

__device__ __forceinline__ unsigned short f2bf(float f) {
  unsigned u = __float_as_uint(f);
  u += 0x7fffu + ((u >> 16) & 1u);  // round-to-nearest-even
  return (unsigned short)(u >> 16);
}
__device__ __forceinline__ float bf2f(unsigned short h) {
  return __uint_as_float(((unsigned)h) << 16);
}
__device__ __forceinline__ float fast_sigmoid(float x) {
  return __builtin_amdgcn_rcpf(1.f + __expf(-x));
}
__device__ __forceinline__ float fast_tanh(float x) {
  return 1.f - 2.f * __builtin_amdgcn_rcpf(__expf(2.f * x) + 1.f);
}

// ------- f32 -> bf16 conversion (vectorized, x and W in one launch) -------
__global__ __launch_bounds__(256) void cvt2_kernel(
    const float* __restrict__ src0, unsigned short* __restrict__ dst0, int n0,
    const float* __restrict__ src1, unsigned short* __restrict__ dst1, int n1) {
  int i = blockIdx.x * 256 + threadIdx.x;
  const float* s;
  unsigned short* d;
  if (i < n0) {
    s = src0; d = dst0;
  } else {
    i -= n0;
    if (i >= n1) return;
    s = src1; d = dst1;
  }
  float4 v = reinterpret_cast<const float4*>(s)[i];
  ushort4 o;
  o.x = f2bf(v.x); o.y = f2bf(v.y); o.z = f2bf(v.z); o.w = f2bf(v.w);
  reinterpret_cast<ushort4*>(d)[i] = o;
}

// ============ 256x256 8-phase bf16 MFMA GEMM (T1+T2+T3/T4+T5) ============
// C[N_ROWS,E] = A[N_ROWS,K] * Bw[E,K]^T, all bf16, f32 accumulate.
// 512 threads = 8 waves (2M x 4N). BK=64. LDS = 2 buffers x (A 32KB + B 32KB).
// Half-tile layout: 2 k-panels (ks=0/1) of [128 rows][32 bf16] (64B rows),
// swizzled byte^=((b>>9)&1)<<5; staged linear-dest with inverse-swz source.
//
// R2 (verified 175.4us, 0 bank conflicts): ds_reads software-pipelined ONE
// PHASE AHEAD — each phase's fragment reads are issued inside the previous
// phase's MFMA region, so the phase-top lgkmcnt(0) is ~free. Phase 2/3 MFMA
// quadrants swapped vs r0 so phase 3 consumes a[4-7]/b[2-3], freeing
// a[0-3]/b[0-1] for the next iteration's hoisted reads (which sit strictly
// after phase 3's vmcnt(4)+barrier = entire next tile drained).
// NOTE (R4 lesson): the hoisted reads are 1 barrier ahead of the next
// buf-write; this is the verified-on-hardware R2 schedule — do not reorder
// reads/stages within phases without re-auditing the write-after-read rule.
#define NT2 32  // K_DIM / 64

__global__ __launch_bounds__(512, 2) void gemm8_kernel(
    const unsigned short* __restrict__ A,
    const unsigned short* __restrict__ Bw,
    unsigned short* __restrict__ C) {
  extern __shared__ __align__(16) char smem[];
  const int tid  = threadIdx.x;
  const int lane = tid & 63;
  const int wave = tid >> 6;
  const int wm = wave >> 2;   // 0..1  (M half)
  const int wn = wave & 3;    // 0..3  (N quarter)

  // XCD-aware mapping: concurrent set per XCD = 4 M-tiles x 8 N-tiles.
  // bid&7 -> XCD; M-tile = xcd*4 + (bid>>3)&3; N-tile = bid>>5. Bijective on 768.
  const int bid = blockIdx.x;
  const int tileM = ((bid & 7) * 4 + ((bid >> 3) & 3)) * 256;
  const int tileN = (bid >> 5) * 256;

  // staging: dest byte p = wave*2048 + L*1024 + lane*16 (linear);
  // logical q = p ^ ((p>>9)&1)<<5 -> (panel=q>>13, row=(q>>6)&127, off=q&63)
  const int p0i = wave * 2048 + lane * 16;
  const int p1i = p0i + 1024;
  const int q0i = p0i ^ (((p0i >> 9) & 1) << 5);
  const int q1i = p1i ^ (((p1i >> 9) & 1) << 5);
  const int go0 = ((q0i >> 6) & 127) * 4096 + ((q0i >> 13) << 6) + (q0i & 63);
  const int go1 = ((q1i >> 6) & 127) * 4096 + ((q1i >> 13) << 6) + (q1i & 63);
  const char* Ab = (const char*)A + (size_t)tileM * 4096;
  const char* Bb = (const char*)Bw + (size_t)tileN * 4096;

#define STAGE(kt, h, bufOff)                                                 \
  {                                                                          \
    const char* gs_ = ((h) < 2 ? Ab : Bb) +                                  \
                      (size_t)(((h) & 1) * 128) * 4096 + (size_t)(kt) * 128; \
    char* ds_ = smem + (bufOff) + (h) * 16384 + wave * 2048;                 \
    __builtin_amdgcn_global_load_lds(                                        \
        (const __attribute__((address_space(1))) void*)(gs_ + go0),          \
        (__attribute__((address_space(3))) void*)ds_, 16, 0, 0);             \
    __builtin_amdgcn_global_load_lds(                                        \
        (const __attribute__((address_space(1))) void*)(gs_ + go1),          \
        (__attribute__((address_space(3))) void*)(ds_ + 1024), 16, 0, 0);    \
  }

  // ds_read fragment bases (swizzled)
  const int xbit = ((lane >> 3) & 1) << 5;  // row bit3 -> flip byte bit5
  const int aBase = wm * 16384 +
                    (((lane & 15) * 64 + (lane >> 4) * 16) ^ xbit);
  const int bBase = 32768 + (wn >> 1) * 16384 +
                    ((((wn & 1) * 64 + (lane & 15)) * 64 + (lane >> 4) * 16) ^ xbit);

#define RDA(m, bufOff)                                                          \
  a[m][0] = *reinterpret_cast<const bf16x8*>(smem + (bufOff) + aBase + (m) * 1024);        \
  a[m][1] = *reinterpret_cast<const bf16x8*>(smem + (bufOff) + aBase + (m) * 1024 + 8192);
#define RDB(n, bufOff)                                                          \
  b[n][0] = *reinterpret_cast<const bf16x8*>(smem + (bufOff) + bBase + (n) * 1024);        \
  b[n][1] = *reinterpret_cast<const bf16x8*>(smem + (bufOff) + bBase + (n) * 1024 + 8192);
#define MM(m, n)                                                                \
  acc[m][n] = __builtin_amdgcn_mfma_f32_16x16x32_bf16(a[m][0], b[n][0], acc[m][n], 0, 0, 0); \
  acc[m][n] = __builtin_amdgcn_mfma_f32_16x16x32_bf16(a[m][1], b[n][1], acc[m][n], 0, 0, 0);

  bf16x8 a[8][2], b[4][2];
  f32x4 acc[8][4] = {};

  // prologue: stage tile0 fully + tile1 h0,h1; drain tile0 (8 oldest of 12);
  // then pre-issue phase-0's fragment reads (a[0-3], b[0-1] of tile 0).
  STAGE(0, 0, 0); STAGE(0, 1, 0); STAGE(0, 2, 0); STAGE(0, 3, 0);
  STAGE(1, 0, 65536); STAGE(1, 1, 65536);
  asm volatile("s_waitcnt vmcnt(4)" ::: "memory");
  __builtin_amdgcn_s_barrier();
  RDA(0, 0); RDA(1, 0); RDA(2, 0); RDA(3, 0);
  RDB(0, 0); RDB(1, 0);

  for (int j = 0; j < NT2; ++j) {
    const int buf  = (j & 1) << 16;
    const int nbuf = buf ^ 65536;
    // ---- phase 0: MFMA(0-3 x 0-1); prefetch a[4-7]; stage (j+1,h2) ----
    asm volatile("s_waitcnt lgkmcnt(0)" ::: "memory");
    __builtin_amdgcn_s_setprio(1);
    if (j < NT2 - 1) STAGE(j + 1, 2, nbuf);
    RDA(4, buf); RDA(5, buf); RDA(6, buf); RDA(7, buf);
    MM(0, 0); MM(0, 1); MM(1, 0); MM(1, 1);
    MM(2, 0); MM(2, 1); MM(3, 0); MM(3, 1);
    __builtin_amdgcn_s_setprio(0);
    __builtin_amdgcn_s_barrier();
    // ---- phase 1: MFMA(4-7 x 0-1); prefetch b[2-3]; stage (j+1,h3) ----
    asm volatile("s_waitcnt lgkmcnt(0)" ::: "memory");
    __builtin_amdgcn_s_setprio(1);
    if (j < NT2 - 1) STAGE(j + 1, 3, nbuf);
    RDB(2, buf); RDB(3, buf);
    MM(4, 0); MM(4, 1); MM(5, 0); MM(5, 1);
    MM(6, 0); MM(6, 1); MM(7, 0); MM(7, 1);
    __builtin_amdgcn_s_setprio(0);
    __builtin_amdgcn_s_barrier();
    // ---- phase 2: MFMA(0-3 x 2-3); stage (j+2,h0)->buf ----
    // (buf A-reads all completed by ph1-top lgkm across waves + ph1 barrier)
    asm volatile("s_waitcnt lgkmcnt(0)" ::: "memory");
    __builtin_amdgcn_s_setprio(1);
    if (j < NT2 - 2) STAGE(j + 2, 0, buf);
    MM(0, 2); MM(0, 3); MM(1, 2); MM(1, 3);
    MM(2, 2); MM(2, 3); MM(3, 2); MM(3, 3);
    __builtin_amdgcn_s_setprio(0);
    __builtin_amdgcn_s_barrier();
    // ---- phase 3: stage (j+2,h1)->buf; drain tile j+1; MFMA(4-7 x 2-3);
    //      hoist next iteration's phase-0 reads (a[0-3],b[0-1] from nbuf) ----
    if (j < NT2 - 2) {
      STAGE(j + 2, 1, buf);
      asm volatile("s_waitcnt vmcnt(4)" ::: "memory");   // completes tile j+1
    } else if (j == NT2 - 2) {
      asm volatile("s_waitcnt vmcnt(0)" ::: "memory");
    }
    __builtin_amdgcn_s_barrier();
    __builtin_amdgcn_s_setprio(1);
    RDA(0, nbuf); RDA(1, nbuf); RDA(2, nbuf); RDA(3, nbuf);
    RDB(0, nbuf); RDB(1, nbuf);
    MM(4, 2); MM(4, 3); MM(5, 2); MM(5, 3);
    MM(6, 2); MM(6, 3); MM(7, 2); MM(7, 3);
    __builtin_amdgcn_s_setprio(0);
    __builtin_amdgcn_s_barrier();
  }

  // epilogue: C/D layout col=lane&15, row=(lane>>4)*4+jj
  const int crow = (lane >> 4) * 4;
  const int ccol = lane & 15;
#pragma unroll
  for (int m = 0; m < 8; ++m) {
#pragma unroll
    for (int n = 0; n < 4; ++n) {
#pragma unroll
      for (int jj = 0; jj < 4; ++jj) {
        int row = tileM + wm * 128 + m * 16 + crow + jj;
        int col = tileN + wn * 64 + n * 16 + ccol;
        C[(size_t)row * E_DIM + col] = f2bf(acc[m][n][jj]);
      }
    }
  }
#undef STAGE
#undef RDA
#undef RDB
#undef MM
}

// ---------------- blocked parallel scan ----------------
// P1: per (b,d,chunk) affine composition over CH2 steps.
// R7: vectorized ushort4 loads (4 d's per thread), bf16 A/B outputs.
// Contraction argument: A = prod of 8 sigmoids (~0.004 typ), so bf16
// rounding of A/B does NOT accumulate across the 128-chunk composition.
__global__ __launch_bounds__(256) void scan_p1_kernel(
    const unsigned short* __restrict__ ufr,
    unsigned short* __restrict__ Aout, unsigned short* __restrict__ Bout) {
  const int idx4 = blockIdx.x * 256 + threadIdx.x;  // (b, d/4): 4096 total
  const int s = blockIdx.y;
  const int b = idx4 >> 9;            // 512 d-groups per b
  const int d = (idx4 & 511) * 4;
  const unsigned short* up =
      ufr + ((size_t)(s * CH2) * B_DIM + b) * E_DIM + d;
  float A0 = 1.f, A1 = 1.f, A2 = 1.f, A3 = 1.f;
  float Bv0 = 0.f, Bv1 = 0.f, Bv2 = 0.f, Bv3 = 0.f;
#pragma unroll
  for (int it = 0; it < CH2; ++it) {
    ushort4 uv = *(const ushort4*)up;
    ushort4 fv = *(const ushort4*)(up + D_DIM);
    float f0 = fast_sigmoid(bf2f(fv.x));
    float f1 = fast_sigmoid(bf2f(fv.y));
    float f2 = fast_sigmoid(bf2f(fv.z));
    float f3 = fast_sigmoid(bf2f(fv.w));
    A0 *= f0; Bv0 = f0 * Bv0 + (1.f - f0) * bf2f(uv.x);
    A1 *= f1; Bv1 = f1 * Bv1 + (1.f - f1) * bf2f(uv.y);
    A2 *= f2; Bv2 = f2 * Bv2 + (1.f - f2) * bf2f(uv.z);
    A3 *= f3; Bv3 = f3 * Bv3 + (1.f - f3) * bf2f(uv.w);
    up += (size_t)B_DIM * E_DIM;
  }
  size_t o = (size_t)s * BD + b * D_DIM + d;
  ushort4 ao = {f2bf(A0), f2bf(A1), f2bf(A2), f2bf(A3)};
  ushort4 bo = {f2bf(Bv0), f2bf(Bv1), f2bf(Bv2), f2bf(Bv3)};
  *(ushort4*)(Aout + o) = ao;
  *(ushort4*)(Bout + o) = bo;
}

// P2: compose chunk boundaries sequentially.
// R7: bf16 A/B/cs; 256 blocks x 64 threads (all CUs engaged for latency hiding).
__global__ __launch_bounds__(64) void scan_p2_kernel(
    const float* __restrict__ c0,
    const unsigned short* __restrict__ Ain, const unsigned short* __restrict__ Bin,
    unsigned short* __restrict__ cs, float* __restrict__ cT) {
  const int idx = blockIdx.x * 64 + threadIdx.x;
  float c = c0[idx];
  for (int s = 0; s < S2; ++s) {
    cs[(size_t)s * BD + idx] = f2bf(c);
    c = bf2f(Ain[(size_t)s * BD + idx]) * c + bf2f(Bin[(size_t)s * BD + idx]);
  }
  cT[idx] = c;
}

// P3 fused with GELU+LN: block = (b, chunk); 256 threads cover all D=2048.
// Re-runs CH2 steps from the chunk start state, then per-t block-LN, writes out.
// R6: reads x as bf16 (xb). R7: reads cs as bf16.
__global__ __launch_bounds__(256) void scan_p3ln_kernel(
    const unsigned short* __restrict__ xb,
    const unsigned short* __restrict__ ufr,
    const unsigned short* __restrict__ csb,
    const float* __restrict__ gamma,
    const float* __restrict__ beta,
    float* __restrict__ out) {
  const int b = blockIdx.x & (B_DIM - 1);
  const int s = blockIdx.x >> 3;
  const int tid = threadIdx.x;
  const int lane = tid & 63;
  const int wave = tid >> 6;
  const int d0 = tid * 8;
  __shared__ float red[8];

  float c[8];
  {
    const unsigned short* csp = csb + (size_t)s * BD + b * D_DIM + d0;
    ushort4 v0 = *(const ushort4*)csp;
    ushort4 v1 = *(const ushort4*)(csp + 4);
    c[0]=bf2f(v0.x); c[1]=bf2f(v0.y); c[2]=bf2f(v0.z); c[3]=bf2f(v0.w);
    c[4]=bf2f(v1.x); c[5]=bf2f(v1.y); c[6]=bf2f(v1.z); c[7]=bf2f(v1.w);
  }
  float gam[8], bet[8];
  {
    float4 g0 = *(const float4*)(gamma + d0);
    float4 g1 = *(const float4*)(gamma + d0 + 4);
    float4 b0 = *(const float4*)(beta + d0);
    float4 b1 = *(const float4*)(beta + d0 + 4);
    gam[0]=g0.x; gam[1]=g0.y; gam[2]=g0.z; gam[3]=g0.w;
    gam[4]=g1.x; gam[5]=g1.y; gam[6]=g1.z; gam[7]=g1.w;
    bet[0]=b0.x; bet[1]=b0.y; bet[2]=b0.z; bet[3]=b0.w;
    bet[4]=b1.x; bet[5]=b1.y; bet[6]=b1.z; bet[7]=b1.w;
  }

  for (int it = 0; it < CH2; ++it) {
    const size_t rowo = (size_t)(s * CH2 + it) * B_DIM + b;
    const unsigned short* up = ufr + rowo * E_DIM + d0;
    const unsigned short* xp = xb + rowo * D_DIM + d0;
    ushort4 uv0 = *(const ushort4*)up;
    ushort4 uv1 = *(const ushort4*)(up + 4);
    ushort4 fv0 = *(const ushort4*)(up + D_DIM);
    ushort4 fv1 = *(const ushort4*)(up + D_DIM + 4);
    ushort4 rv0 = *(const ushort4*)(up + 2 * D_DIM);
    ushort4 rv1 = *(const ushort4*)(up + 2 * D_DIM + 4);
    ushort4 xv0 = *(const ushort4*)xp;
    ushort4 xv1 = *(const ushort4*)(xp + 4);
    unsigned short uu[8] = {uv0.x, uv0.y, uv0.z, uv0.w, uv1.x, uv1.y, uv1.z, uv1.w};
    unsigned short ff[8] = {fv0.x, fv0.y, fv0.z, fv0.w, fv1.x, fv1.y, fv1.z, fv1.w};
    unsigned short rr[8] = {rv0.x, rv0.y, rv0.z, rv0.w, rv1.x, rv1.y, rv1.z, rv1.w};
    unsigned short xx[8] = {xv0.x, xv0.y, xv0.z, xv0.w, xv1.x, xv1.y, xv1.z, xv1.w};

    float g[8];
    float s1 = 0.f, sq = 0.f;
#pragma unroll
    for (int jj = 0; jj < 8; ++jj) {
      float f = fast_sigmoid(bf2f(ff[jj]));
      float r = fast_sigmoid(bf2f(rr[jj]));
      c[jj] = f * c[jj] + (1.f - f) * bf2f(uu[jj]);
      float h = r * fast_tanh(c[jj]) + (1.f - r) * bf2f(xx[jj]);
      float gg = 0.5f * h * (1.f + erff(h * 0.70710678118654752f));
      g[jj] = gg;
      s1 += gg;
      sq += gg * gg;
    }
#pragma unroll
    for (int off = 32; off; off >>= 1) {
      s1 += __shfl_xor(s1, off);
      sq += __shfl_xor(sq, off);
    }
    if (lane == 0) { red[wave] = s1; red[4 + wave] = sq; }
    __syncthreads();
    float S1 = red[0] + red[1] + red[2] + red[3];
    float Sq = red[4] + red[5] + red[6] + red[7];
    __syncthreads();  // red reused next iteration
    float mean = S1 * (1.f / D_DIM);
    float var  = Sq * (1.f / D_DIM) - mean * mean;
    float inv = rsqrtf(var + LN_EPS);

    float* op = out + rowo * D_DIM + d0;
    float4 o0 = {(g[0] - mean) * inv * gam[0] + bet[0],
                 (g[1] - mean) * inv * gam[1] + bet[1],
                 (g[2] - mean) * inv * gam[2] + bet[2],
                 (g[3] - mean) * inv * gam[3] + bet[3]};
    float4 o1 = {(g[4] - mean) * inv * gam[4] + bet[4],
                 (g[5] - mean) * inv * gam[5] + bet[5],
                 (g[6] - mean) * inv * gam[6] + bet[6],
                 (g[7] - mean) * inv * gam[7] + bet[7]};
    *(float4*)op = o0;
    *(float4*)(op + 4) = o1;
  }
}

extern "C" void kernel_launch(void* const* d_in, const int* in_sizes, int n_in,
                              void* d_out, int out_size, void* d_ws, size_t ws_size,
                              hipStream_t stream) {
  const float* x     = (const float*)d_in[0];
  const float* c0    = (const float*)d_in[1];
  const float* W     = (const float*)d_in[2];
  const float* gamma = (const float*)d_in[3];
  const float* beta  = (const float*)d_in[4];
  float* out = (float*)d_out;
  float* cT  = out + (size_t)N_ROWS * D_DIM;

  unsigned short* ufr = (unsigned short*)d_ws;                 // [N_ROWS][E] bf16
  unsigned short* xb  = ufr + (size_t)N_ROWS * E_DIM;          // [N_ROWS][K] bf16
  unsigned short* wb  = xb + (size_t)N_ROWS * K_DIM;           // [E][K] bf16

  // scan scratch reuses wb region (dead after gemm; xb stays live for p3):
  // 3 * S2*BD*2 = 12.6MB < 25.2MB (wb size). All bf16 now.
  unsigned short* Abuf = wb;
  unsigned short* Bbuf = Abuf + (size_t)S2 * BD;
  unsigned short* csb  = Bbuf + (size_t)S2 * BD;

  int nx4 = N_ROWS * K_DIM / 4;
  int nw4 = E_DIM * K_DIM / 4;
  cvt2_kernel<<<(nx4 + nw4 + 255) / 256, 256, 0, stream>>>(x, xb, nx4, W, wb, nw4);

  (void)hipFuncSetAttribute((const void*)gemm8_kernel,
                            hipFuncAttributeMaxDynamicSharedMemorySize, 131072);
  gemm8_kernel<<<768, 512, 131072, stream>>>(xb, wb, ufr);

  dim3 sg(BD / 4 / 256, S2);  // (16, 128)
  scan_p1_kernel<<<sg, 256, 0, stream>>>(ufr, Abuf, Bbuf);
  scan_p2_kernel<<<BD / 64, 64, 0, stream>>>(c0, Abuf, Bbuf, csb, cT);
  scan_p3ln_kernel<<<B_DIM * S2, 256, 0, stream>>>(xb, ufr, csb, gamma, beta, out);
}

// Round 8
// 264.403 us; speedup vs baseline: 1.0879x; 1.0094x over previous
//
#include <hip/hip_runtime.h>
#include <hip/hip_bf16.h>

#define T_DIM 1024
#define B_DIM 8
#define D_DIM 2048
#define E_DIM 6144   // 3*D
#define N_ROWS 8192  // T*B
#define K_DIM 2048
#define LN_EPS 1e-5f

#define S2  128   // scan chunks
#define CH2 8     // T per chunk
#define BD (B_DIM * D_DIM)  // 16384

typedef short bf16x8 __attribute__((ext_vector_type(8)));
typedef unsigned short u16x8 __attribute__((ext_vector_type(8)));
typedef float f32x4 __attribute__((ext_vector_type(4)));

__device__ __forceinline__ unsigned short f2bf(float f) {
  unsigned u = __float_as_uint(f);
  u += 0x7fffu + ((u >> 16) & 1u);  // round-to-nearest-even
  return (unsigned short)(u >> 16);
}
__device__ __forceinline__ float bf2f(unsigned short h) {
  return __uint_as_float(((unsigned)h) << 16);
}
__device__ __forceinline__ float fast_sigmoid(float x) {
  return __builtin_amdgcn_rcpf(1.f + __expf(-x));
}
__device__ __forceinline__ float fast_tanh(float x) {
  return 1.f - 2.f * __builtin_amdgcn_rcpf(__expf(2.f * x) + 1.f);
}

// ------- f32 -> bf16 conversion (8 elems/thread, 16B stores) -------
__global__ __launch_bounds__(256) void cvt2_kernel(
    const float* __restrict__ src0, unsigned short* __restrict__ dst0, int n0,
    const float* __restrict__ src1, unsigned short* __restrict__ dst1, int n1) {
  int i = blockIdx.x * 256 + threadIdx.x;  // group of 8 floats
  const float* s;
  unsigned short* d;
  if (i < n0) {
    s = src0; d = dst0;
  } else {
    i -= n0;
    if (i >= n1) return;
    s = src1; d = dst1;
  }
  float4 v0 = reinterpret_cast<const float4*>(s)[i * 2];
  float4 v1 = reinterpret_cast<const float4*>(s)[i * 2 + 1];
  u16x8 o;
  o[0] = f2bf(v0.x); o[1] = f2bf(v0.y); o[2] = f2bf(v0.z); o[3] = f2bf(v0.w);
  o[4] = f2bf(v1.x); o[5] = f2bf(v1.y); o[6] = f2bf(v1.z); o[7] = f2bf(v1.w);
  *reinterpret_cast<u16x8*>(d + (size_t)i * 8) = o;
}

// ============ 256x256 8-phase bf16 MFMA GEMM (T1+T2+T3/T4+T5) ============
// C[N_ROWS,E] = A[N_ROWS,K] * Bw[E,K]^T, all bf16, f32 accumulate.
// 512 threads = 8 waves (2M x 4N). BK=64. LDS = 2 buffers x (A 32KB + B 32KB).
// Half-tile layout: 2 k-panels (ks=0/1) of [128 rows][32 bf16] (64B rows),
// swizzled byte^=((b>>9)&1)<<5; staged linear-dest with inverse-swz source.
//
// R2 (verified 175.4us, 0 bank conflicts): ds_reads software-pipelined ONE
// PHASE AHEAD — each phase's fragment reads are issued inside the previous
// phase's MFMA region, so the phase-top lgkmcnt(0) is ~free. Phase 2/3 MFMA
// quadrants swapped vs r0 so phase 3 consumes a[4-7]/b[2-3], freeing
// a[0-3]/b[0-1] for the next iteration's hoisted reads (which sit strictly
// after phase 3's vmcnt(4)+barrier = entire next tile drained).
// NOTE (R4 lesson): the hoisted reads are 1 barrier ahead of the next
// buf-write; this is the verified-on-hardware R2 schedule — do not reorder
// reads/stages within phases without re-auditing the write-after-read rule.
#define NT2 32  // K_DIM / 64

__global__ __launch_bounds__(512, 2) void gemm8_kernel(
    const unsigned short* __restrict__ A,
    const unsigned short* __restrict__ Bw,
    unsigned short* __restrict__ C) {
  extern __shared__ __align__(16) char smem[];
  const int tid  = threadIdx.x;
  const int lane = tid & 63;
  const int wave = tid >> 6;
  const int wm = wave >> 2;   // 0..1  (M half)
  const int wn = wave & 3;    // 0..3  (N quarter)

  // XCD-aware mapping: concurrent set per XCD = 4 M-tiles x 8 N-tiles.
  // bid&7 -> XCD; M-tile = xcd*4 + (bid>>3)&3; N-tile = bid>>5. Bijective on 768.
  const int bid = blockIdx.x;
  const int tileM = ((bid & 7) * 4 + ((bid >> 3) & 3)) * 256;
  const int tileN = (bid >> 5) * 256;

  // staging: dest byte p = wave*2048 + L*1024 + lane*16 (linear);
  // logical q = p ^ ((p>>9)&1)<<5 -> (panel=q>>13, row=(q>>6)&127, off=q&63)
  const int p0i = wave * 2048 + lane * 16;
  const int p1i = p0i + 1024;
  const int q0i = p0i ^ (((p0i >> 9) & 1) << 5);
  const int q1i = p1i ^ (((p1i >> 9) & 1) << 5);
  const int go0 = ((q0i >> 6) & 127) * 4096 + ((q0i >> 13) << 6) + (q0i & 63);
  const int go1 = ((q1i >> 6) & 127) * 4096 + ((q1i >> 13) << 6) + (q1i & 63);
  const char* Ab = (const char*)A + (size_t)tileM * 4096;
  const char* Bb = (const char*)Bw + (size_t)tileN * 4096;

#define STAGE(kt, h, bufOff)                                                 \
  {                                                                          \
    const char* gs_ = ((h) < 2 ? Ab : Bb) +                                  \
                      (size_t)(((h) & 1) * 128) * 4096 + (size_t)(kt) * 128; \
    char* ds_ = smem + (bufOff) + (h) * 16384 + wave * 2048;                 \
    __builtin_amdgcn_global_load_lds(                                        \
        (const __attribute__((address_space(1))) void*)(gs_ + go0),          \
        (__attribute__((address_space(3))) void*)ds_, 16, 0, 0);             \
    __builtin_amdgcn_global_load_lds(                                        \
        (const __attribute__((address_space(1))) void*)(gs_ + go1),          \
        (__attribute__((address_space(3))) void*)(ds_ + 1024), 16, 0, 0);    \
  }

  // ds_read fragment bases (swizzled)
  const int xbit = ((lane >> 3) & 1) << 5;  // row bit3 -> flip byte bit5
  const int aBase = wm * 16384 +
                    (((lane & 15) * 64 + (lane >> 4) * 16) ^ xbit);
  const int bBase = 32768 + (wn >> 1) * 16384 +
                    ((((wn & 1) * 64 + (lane & 15)) * 64 + (lane >> 4) * 16) ^ xbit);

#define RDA(m, bufOff)                                                          \
  a[m][0] = *reinterpret_cast<const bf16x8*>(smem + (bufOff) + aBase + (m) * 1024);        \
  a[m][1] = *reinterpret_cast<const bf16x8*>(smem + (bufOff) + aBase + (m) * 1024 + 8192);
#define RDB(n, bufOff)                                                          \
  b[n][0] = *reinterpret_cast<const bf16x8*>(smem + (bufOff) + bBase + (n) * 1024);        \
  b[n][1] = *reinterpret_cast<const bf16x8*>(smem + (bufOff) + bBase + (n) * 1024 + 8192);
#define MM(m, n)                                                                \
  acc[m][n] = __builtin_amdgcn_mfma_f32_16x16x32_bf16(a[m][0], b[n][0], acc[m][n], 0, 0, 0); \
  acc[m][n] = __builtin_amdgcn_mfma_f32_16x16x32_bf16(a[m][1], b[n][1], acc[m][n], 0, 0, 0);

  bf16x8 a[8][2], b[4][2];
  f32x4 acc[8][4] = {};

  // prologue: stage tile0 fully + tile1 h0,h1; drain tile0 (8 oldest of 12);
  // then pre-issue phase-0's fragment reads (a[0-3], b[0-1] of tile 0).
  STAGE(0, 0, 0); STAGE(0, 1, 0); STAGE(0, 2, 0); STAGE(0, 3, 0);
  STAGE(1, 0, 65536); STAGE(1, 1, 65536);
  asm volatile("s_waitcnt vmcnt(4)" ::: "memory");
  __builtin_amdgcn_s_barrier();
  RDA(0, 0); RDA(1, 0); RDA(2, 0); RDA(3, 0);
  RDB(0, 0); RDB(1, 0);

  for (int j = 0; j < NT2; ++j) {
    const int buf  = (j & 1) << 16;
    const int nbuf = buf ^ 65536;
    // ---- phase 0: MFMA(0-3 x 0-1); prefetch a[4-7]; stage (j+1,h2) ----
    asm volatile("s_waitcnt lgkmcnt(0)" ::: "memory");
    __builtin_amdgcn_s_setprio(1);
    if (j < NT2 - 1) STAGE(j + 1, 2, nbuf);
    RDA(4, buf); RDA(5, buf); RDA(6, buf); RDA(7, buf);
    MM(0, 0); MM(0, 1); MM(1, 0); MM(1, 1);
    MM(2, 0); MM(2, 1); MM(3, 0); MM(3, 1);
    __builtin_amdgcn_s_setprio(0);
    __builtin_amdgcn_s_barrier();
    // ---- phase 1: MFMA(4-7 x 0-1); prefetch b[2-3]; stage (j+1,h3) ----
    asm volatile("s_waitcnt lgkmcnt(0)" ::: "memory");
    __builtin_amdgcn_s_setprio(1);
    if (j < NT2 - 1) STAGE(j + 1, 3, nbuf);
    RDB(2, buf); RDB(3, buf);
    MM(4, 0); MM(4, 1); MM(5, 0); MM(5, 1);
    MM(6, 0); MM(6, 1); MM(7, 0); MM(7, 1);
    __builtin_amdgcn_s_setprio(0);
    __builtin_amdgcn_s_barrier();
    // ---- phase 2: MFMA(0-3 x 2-3); stage (j+2,h0)->buf ----
    // (buf A-reads all completed by ph1-top lgkm across waves + ph1 barrier)
    asm volatile("s_waitcnt lgkmcnt(0)" ::: "memory");
    __builtin_amdgcn_s_setprio(1);
    if (j < NT2 - 2) STAGE(j + 2, 0, buf);
    MM(0, 2); MM(0, 3); MM(1, 2); MM(1, 3);
    MM(2, 2); MM(2, 3); MM(3, 2); MM(3, 3);
    __builtin_amdgcn_s_setprio(0);
    __builtin_amdgcn_s_barrier();
    // ---- phase 3: stage (j+2,h1)->buf; drain tile j+1; MFMA(4-7 x 2-3);
    //      hoist next iteration's phase-0 reads (a[0-3],b[0-1] from nbuf) ----
    if (j < NT2 - 2) {
      STAGE(j + 2, 1, buf);
      asm volatile("s_waitcnt vmcnt(4)" ::: "memory");   // completes tile j+1
    } else if (j == NT2 - 2) {
      asm volatile("s_waitcnt vmcnt(0)" ::: "memory");
    }
    __builtin_amdgcn_s_barrier();
    __builtin_amdgcn_s_setprio(1);
    RDA(0, nbuf); RDA(1, nbuf); RDA(2, nbuf); RDA(3, nbuf);
    RDB(0, nbuf); RDB(1, nbuf);
    MM(4, 2); MM(4, 3); MM(5, 2); MM(5, 3);
    MM(6, 2); MM(6, 3); MM(7, 2); MM(7, 3);
    __builtin_amdgcn_s_setprio(0);
    __builtin_amdgcn_s_barrier();
  }

  // epilogue: C/D layout col=lane&15, row=(lane>>4)*4+jj
  const int crow = (lane >> 4) * 4;
  const int ccol = lane & 15;
#pragma unroll
  for (int m = 0; m < 8; ++m) {
#pragma unroll
    for (int n = 0; n < 4; ++n) {
#pragma unroll
      for (int jj = 0; jj < 4; ++jj) {
        int row = tileM + wm * 128 + m * 16 + crow + jj;
        int col = tileN + wn * 64 + n * 16 + ccol;
        C[(size_t)row * E_DIM + col] = f2bf(acc[m][n][jj]);
      }
    }
  }
#undef STAGE
#undef RDA
#undef RDB
#undef MM
}

// ---------------- blocked parallel scan ----------------
// P1: per (b,d,chunk) affine composition over CH2 steps.
// R8: 8 d's per thread, bf16x8 16B loads (coalescing sweet spot).
__global__ __launch_bounds__(256) void scan_p1_kernel(
    const unsigned short* __restrict__ ufr,
    unsigned short* __restrict__ Aout, unsigned short* __restrict__ Bout) {
  const int idx8 = blockIdx.x * 256 + threadIdx.x;  // (b, d/8): 2048 total
  const int s = blockIdx.y;
  const int b = idx8 >> 8;            // 256 d-groups per b
  const int d = (idx8 & 255) * 8;
  const unsigned short* up =
      ufr + ((size_t)(s * CH2) * B_DIM + b) * E_DIM + d;
  float Av[8], Bv[8];
#pragma unroll
  for (int q = 0; q < 8; ++q) { Av[q] = 1.f; Bv[q] = 0.f; }
#pragma unroll
  for (int it = 0; it < CH2; ++it) {
    u16x8 uv = *reinterpret_cast<const u16x8*>(up);
    u16x8 fv = *reinterpret_cast<const u16x8*>(up + D_DIM);
#pragma unroll
    for (int q = 0; q < 8; ++q) {
      float f = fast_sigmoid(bf2f(fv[q]));
      Av[q] *= f;
      Bv[q] = f * Bv[q] + (1.f - f) * bf2f(uv[q]);
    }
    up += (size_t)B_DIM * E_DIM;
  }
  size_t o = (size_t)s * BD + b * D_DIM + d;
  u16x8 ao, bo;
#pragma unroll
  for (int q = 0; q < 8; ++q) { ao[q] = f2bf(Av[q]); bo[q] = f2bf(Bv[q]); }
  *reinterpret_cast<u16x8*>(Aout + o) = ao;
  *reinterpret_cast<u16x8*>(Bout + o) = bo;
}

// P2: compose chunk boundaries sequentially.
// R8: batch-8 double-buffered prefetch. The A/B loads for chunk s are
// independent of the running c, so each batch of 16 loads is issued while
// the previous batch's 8 FMAs retire — hides the ~200-500cy L2/L3 latency
// that previously serialized 128 times. Named arrays + full unroll keep
// everything in registers (rule #20).
__global__ __launch_bounds__(64) void scan_p2_kernel(
    const float* __restrict__ c0,
    const unsigned short* __restrict__ Ain, const unsigned short* __restrict__ Bin,
    unsigned short* __restrict__ cs, float* __restrict__ cT) {
  const int idx = blockIdx.x * 64 + threadIdx.x;
  float c = c0[idx];
  unsigned short aP[8], bP[8], aQ[8], bQ[8];
#define LOADB(AA, BB, sb)                                          \
  _Pragma("unroll")                                                \
  for (int q = 0; q < 8; ++q) {                                    \
    AA[q] = Ain[(size_t)((sb) + q) * BD + idx];                    \
    BB[q] = Bin[(size_t)((sb) + q) * BD + idx];                    \
  }
#define COMPB(AA, BB, sb)                                          \
  _Pragma("unroll")                                                \
  for (int q = 0; q < 8; ++q) {                                    \
    cs[(size_t)((sb) + q) * BD + idx] = f2bf(c);                   \
    c = bf2f(AA[q]) * c + bf2f(BB[q]);                             \
  }
  LOADB(aP, bP, 0);
  for (int sb = 0; sb < S2; sb += 16) {
    LOADB(aQ, bQ, sb + 8);
    COMPB(aP, bP, sb);
    if (sb + 16 < S2) { LOADB(aP, bP, sb + 16); }
    COMPB(aQ, bQ, sb + 8);
  }
#undef LOADB
#undef COMPB
  cT[idx] = c;
}

// P3 fused with GELU+LN: block = (b, chunk); 256 threads cover all D=2048.
// Re-runs CH2 steps from the chunk start state, then per-t block-LN, writes out.
// R6: x as bf16. R7: cs as bf16. R8: all bf16 loads widened to 16B (u16x8).
__global__ __launch_bounds__(256) void scan_p3ln_kernel(
    const unsigned short* __restrict__ xb,
    const unsigned short* __restrict__ ufr,
    const unsigned short* __restrict__ csb,
    const float* __restrict__ gamma,
    const float* __restrict__ beta,
    float* __restrict__ out) {
  const int b = blockIdx.x & (B_DIM - 1);
  const int s = blockIdx.x >> 3;
  const int tid = threadIdx.x;
  const int lane = tid & 63;
  const int wave = tid >> 6;
  const int d0 = tid * 8;
  __shared__ float red[8];

  float c[8];
  {
    u16x8 v = *reinterpret_cast<const u16x8*>(csb + (size_t)s * BD + b * D_DIM + d0);
#pragma unroll
    for (int q = 0; q < 8; ++q) c[q] = bf2f(v[q]);
  }
  float gam[8], bet[8];
  {
    float4 g0 = *(const float4*)(gamma + d0);
    float4 g1 = *(const float4*)(gamma + d0 + 4);
    float4 b0 = *(const float4*)(beta + d0);
    float4 b1 = *(const float4*)(beta + d0 + 4);
    gam[0]=g0.x; gam[1]=g0.y; gam[2]=g0.z; gam[3]=g0.w;
    gam[4]=g1.x; gam[5]=g1.y; gam[6]=g1.z; gam[7]=g1.w;
    bet[0]=b0.x; bet[1]=b0.y; bet[2]=b0.z; bet[3]=b0.w;
    bet[4]=b1.x; bet[5]=b1.y; bet[6]=b1.z; bet[7]=b1.w;
  }

  for (int it = 0; it < CH2; ++it) {
    const size_t rowo = (size_t)(s * CH2 + it) * B_DIM + b;
    const unsigned short* up = ufr + rowo * E_DIM + d0;
    u16x8 uv = *reinterpret_cast<const u16x8*>(up);
    u16x8 fv = *reinterpret_cast<const u16x8*>(up + D_DIM);
    u16x8 rv = *reinterpret_cast<const u16x8*>(up + 2 * D_DIM);
    u16x8 xv = *reinterpret_cast<const u16x8*>(xb + rowo * D_DIM + d0);

    float g[8];
    float s1 = 0.f, sq = 0.f;
#pragma unroll
    for (int jj = 0; jj < 8; ++jj) {
      float f = fast_sigmoid(bf2f(fv[jj]));
      float r = fast_sigmoid(bf2f(rv[jj]));
      c[jj] = f * c[jj] + (1.f - f) * bf2f(uv[jj]);
      float h = r * fast_tanh(c[jj]) + (1.f - r) * bf2f(xv[jj]);
      float gg = 0.5f * h * (1.f + erff(h * 0.70710678118654752f));
      g[jj] = gg;
      s1 += gg;
      sq += gg * gg;
    }
#pragma unroll
    for (int off = 32; off; off >>= 1) {
      s1 += __shfl_xor(s1, off);
      sq += __shfl_xor(sq, off);
    }
    if (lane == 0) { red[wave] = s1; red[4 + wave] = sq; }
    __syncthreads();
    float S1 = red[0] + red[1] + red[2] + red[3];
    float Sq = red[4] + red[5] + red[6] + red[7];
    __syncthreads();  // red reused next iteration
    float mean = S1 * (1.f / D_DIM);
    float var  = Sq * (1.f / D_DIM) - mean * mean;
    float inv = rsqrtf(var + LN_EPS);

    float* op = out + rowo * D_DIM + d0;
    float4 o0 = {(g[0] - mean) * inv * gam[0] + bet[0],
                 (g[1] - mean) * inv * gam[1] + bet[1],
                 (g[2] - mean) * inv * gam[2] + bet[2],
                 (g[3] - mean) * inv * gam[3] + bet[3]};
    float4 o1 = {(g[4] - mean) * inv * gam[4] + bet[4],
                 (g[5] - mean) * inv * gam[5] + bet[5],
                 (g[6] - mean) * inv * gam[6] + bet[6],
                 (g[7] - mean) * inv * gam[7] + bet[7]};
    *(float4*)op = o0;
    *(float4*)(op + 4) = o1;
  }
}

extern "C" void kernel_launch(void* const* d_in, const int* in_sizes, int n_in,
                              void* d_out, int out_size, void* d_ws, size_t ws_size,
                              hipStream_t stream) {
  const float* x     = (const float*)d_in[0];
  const float* c0    = (const float*)d_in[1];
  const float* W     = (const float*)d_in[2];
  const float* gamma = (const float*)d_in[3];
  const float* beta  = (const float*)d_in[4];
  float* out = (float*)d_out;
  float* cT  = out + (size_t)N_ROWS * D_DIM;

  unsigned short* ufr = (unsigned short*)d_ws;                 // [N_ROWS][E] bf16
  unsigned short* xb  = ufr + (size_t)N_ROWS * E_DIM;          // [N_ROWS][K] bf16
  unsigned short* wb  = xb + (size_t)N_ROWS * K_DIM;           // [E][K] bf16

  // scan scratch reuses wb region (dead after gemm; xb stays live for p3):
  // 3 * S2*BD*2 = 12.6MB < 25.2MB (wb size). All bf16.
  unsigned short* Abuf = wb;
  unsigned short* Bbuf = Abuf + (size_t)S2 * BD;
  unsigned short* csb  = Bbuf + (size_t)S2 * BD;

  int nx8 = N_ROWS * K_DIM / 8;
  int nw8 = E_DIM * K_DIM / 8;
  cvt2_kernel<<<(nx8 + nw8 + 255) / 256, 256, 0, stream>>>(x, xb, nx8, W, wb, nw8);

  (void)hipFuncSetAttribute((const void*)gemm8_kernel,
                            hipFuncAttributeMaxDynamicSharedMemorySize, 131072);
  gemm8_kernel<<<768, 512, 131072, stream>>>(xb, wb, ufr);

  dim3 sg(BD / 8 / 256, S2);  // (8, 128)
  scan_p1_kernel<<<sg, 256, 0, stream>>>(ufr, Abuf, Bbuf);
  scan_p2_kernel<<<BD / 64, 64, 0, stream>>>(c0, Abuf, Bbuf, csb, cT);
  scan_p3ln_kernel<<<B_DIM * S2, 256, 0, stream>>>(xb, ufr, csb, gamma, beta, out);
}

// Round 9
// 258.179 us; speedup vs baseline: 1.1141x; 1.0241x over previous
//
#include <hip/hip_runtime.h>
#include <hip/hip_bf16.h>

#define T_DIM 1024
#define B_DIM 8
#define D_DIM 2048
#define E_DIM 6144   // 3*D
#define N_ROWS 8192  // T*B
#define K_DIM 2048
#define LN_EPS 1e-5f

#define S2  128   // scan chunks
#define CH2 8     // T per chunk
#define BD (B_DIM * D_DIM)  // 16384

typedef short bf16x8 __attribute__((ext_vector_type(8)));
typedef unsigned short u16x8 __attribute__((ext_vector_type(8)));
typedef float f32x4 __attribute__((ext_vector_type(4)));

__device__ __forceinline__ unsigned short f2bf(float f) {
  unsigned u = __float_as_uint(f);
  u += 0x7fffu + ((u >> 16) & 1u);  // round-to-nearest-even
  return (unsigned short)(u >> 16);
}
__device__ __forceinline__ float bf2f(unsigned short h) {
  return __uint_as_float(((unsigned)h) << 16);
}
__device__ __forceinline__ float fast_sigmoid(float x) {
  return __builtin_amdgcn_rcpf(1.f + __expf(-x));
}
__device__ __forceinline__ float fast_tanh(float x) {
  return 1.f - 2.f * __builtin_amdgcn_rcpf(__expf(2.f * x) + 1.f);
}

// ------- f32 -> bf16 conversion (8 elems/thread, 16B stores) -------
__global__ __launch_bounds__(256) void cvt2_kernel(
    const float* __restrict__ src0, unsigned short* __restrict__ dst0, int n0,
    const float* __restrict__ src1, unsigned short* __restrict__ dst1, int n1) {
  int i = blockIdx.x * 256 + threadIdx.x;  // group of 8 floats
  const float* s;
  unsigned short* d;
  if (i < n0) {
    s = src0; d = dst0;
  } else {
    i -= n0;
    if (i >= n1) return;
    s = src1; d = dst1;
  }
  float4 v0 = reinterpret_cast<const float4*>(s)[i * 2];
  float4 v1 = reinterpret_cast<const float4*>(s)[i * 2 + 1];
  u16x8 o;
  o[0] = f2bf(v0.x); o[1] = f2bf(v0.y); o[2] = f2bf(v0.z); o[3] = f2bf(v0.w);
  o[4] = f2bf(v1.x); o[5] = f2bf(v1.y); o[6] = f2bf(v1.z); o[7] = f2bf(v1.w);
  *reinterpret_cast<u16x8*>(d + (size_t)i * 8) = o;
}

// ============ 256x256 8-phase bf16 MFMA GEMM (T1+T2+T3/T4+T5) ============
// C[N_ROWS,E] = A[N_ROWS,K] * Bw[E,K]^T, all bf16, f32 accumulate.
// 512 threads = 8 waves (2M x 4N). BK=64. LDS = 2 buffers x (A 32KB + B 32KB).
// Half-tile layout: 2 k-panels (ks=0/1) of [128 rows][32 bf16] (64B rows),
// swizzled byte^=((b>>9)&1)<<5; staged linear-dest with inverse-swz source.
//
// R2 (verified 175.4us, 0 bank conflicts): ds_reads software-pipelined ONE
// PHASE AHEAD — each phase's fragment reads are issued inside the previous
// phase's MFMA region. R9: explicit phase-top lgkmcnt(0) asm removed — the
// compiler emits fine-grained per-use lgkmcnt(N), letting the first MFMAs of
// a phase start as soon as their own fragments land instead of waiting for
// all 10-12 reads. No memory op moves across any barrier; the R2
// write-after-read audit (region overwrite >=2 barriers after consumption)
// is unchanged.
// NOTE (R4 lesson): do not reorder reads/stages across phases without
// re-auditing the write-after-read rule.
#define NT2 32  // K_DIM / 64

__global__ __launch_bounds__(512, 2) void gemm8_kernel(
    const unsigned short* __restrict__ A,
    const unsigned short* __restrict__ Bw,
    unsigned short* __restrict__ C) {
  extern __shared__ __align__(16) char smem[];
  const int tid  = threadIdx.x;
  const int lane = tid & 63;
  const int wave = tid >> 6;
  const int wm = wave >> 2;   // 0..1  (M half)
  const int wn = wave & 3;    // 0..3  (N quarter)

  // XCD-aware mapping: concurrent set per XCD = 4 M-tiles x 8 N-tiles.
  // bid&7 -> XCD; M-tile = xcd*4 + (bid>>3)&3; N-tile = bid>>5. Bijective on 768.
  const int bid = blockIdx.x;
  const int tileM = ((bid & 7) * 4 + ((bid >> 3) & 3)) * 256;
  const int tileN = (bid >> 5) * 256;

  // staging: dest byte p = wave*2048 + L*1024 + lane*16 (linear);
  // logical q = p ^ ((p>>9)&1)<<5 -> (panel=q>>13, row=(q>>6)&127, off=q&63)
  const int p0i = wave * 2048 + lane * 16;
  const int p1i = p0i + 1024;
  const int q0i = p0i ^ (((p0i >> 9) & 1) << 5);
  const int q1i = p1i ^ (((p1i >> 9) & 1) << 5);
  const int go0 = ((q0i >> 6) & 127) * 4096 + ((q0i >> 13) << 6) + (q0i & 63);
  const int go1 = ((q1i >> 6) & 127) * 4096 + ((q1i >> 13) << 6) + (q1i & 63);
  const char* Ab = (const char*)A + (size_t)tileM * 4096;
  const char* Bb = (const char*)Bw + (size_t)tileN * 4096;

#define STAGE(kt, h, bufOff)                                                 \
  {                                                                          \
    const char* gs_ = ((h) < 2 ? Ab : Bb) +                                  \
                      (size_t)(((h) & 1) * 128) * 4096 + (size_t)(kt) * 128; \
    char* ds_ = smem + (bufOff) + (h) * 16384 + wave * 2048;                 \
    __builtin_amdgcn_global_load_lds(                                        \
        (const __attribute__((address_space(1))) void*)(gs_ + go0),          \
        (__attribute__((address_space(3))) void*)ds_, 16, 0, 0);             \
    __builtin_amdgcn_global_load_lds(                                        \
        (const __attribute__((address_space(1))) void*)(gs_ + go1),          \
        (__attribute__((address_space(3))) void*)(ds_ + 1024), 16, 0, 0);    \
  }

  // ds_read fragment bases (swizzled)
  const int xbit = ((lane >> 3) & 1) << 5;  // row bit3 -> flip byte bit5
  const int aBase = wm * 16384 +
                    (((lane & 15) * 64 + (lane >> 4) * 16) ^ xbit);
  const int bBase = 32768 + (wn >> 1) * 16384 +
                    ((((wn & 1) * 64 + (lane & 15)) * 64 + (lane >> 4) * 16) ^ xbit);

#define RDA(m, bufOff)                                                          \
  a[m][0] = *reinterpret_cast<const bf16x8*>(smem + (bufOff) + aBase + (m) * 1024);        \
  a[m][1] = *reinterpret_cast<const bf16x8*>(smem + (bufOff) + aBase + (m) * 1024 + 8192);
#define RDB(n, bufOff)                                                          \
  b[n][0] = *reinterpret_cast<const bf16x8*>(smem + (bufOff) + bBase + (n) * 1024);        \
  b[n][1] = *reinterpret_cast<const bf16x8*>(smem + (bufOff) + bBase + (n) * 1024 + 8192);
#define MM(m, n)                                                                \
  acc[m][n] = __builtin_amdgcn_mfma_f32_16x16x32_bf16(a[m][0], b[n][0], acc[m][n], 0, 0, 0); \
  acc[m][n] = __builtin_amdgcn_mfma_f32_16x16x32_bf16(a[m][1], b[n][1], acc[m][n], 0, 0, 0);

  bf16x8 a[8][2], b[4][2];
  f32x4 acc[8][4] = {};

  // prologue: stage tile0 fully + tile1 h0,h1; drain tile0 (8 oldest of 12);
  // then pre-issue phase-0's fragment reads (a[0-3], b[0-1] of tile 0).
  STAGE(0, 0, 0); STAGE(0, 1, 0); STAGE(0, 2, 0); STAGE(0, 3, 0);
  STAGE(1, 0, 65536); STAGE(1, 1, 65536);
  asm volatile("s_waitcnt vmcnt(4)" ::: "memory");
  __builtin_amdgcn_s_barrier();
  RDA(0, 0); RDA(1, 0); RDA(2, 0); RDA(3, 0);
  RDB(0, 0); RDB(1, 0);

  for (int j = 0; j < NT2; ++j) {
    const int buf  = (j & 1) << 16;
    const int nbuf = buf ^ 65536;
    // ---- phase 0: MFMA(0-3 x 0-1); prefetch a[4-7]; stage (j+1,h2) ----
    __builtin_amdgcn_s_setprio(1);
    if (j < NT2 - 1) STAGE(j + 1, 2, nbuf);
    RDA(4, buf); RDA(5, buf); RDA(6, buf); RDA(7, buf);
    MM(0, 0); MM(0, 1); MM(1, 0); MM(1, 1);
    MM(2, 0); MM(2, 1); MM(3, 0); MM(3, 1);
    __builtin_amdgcn_s_setprio(0);
    __builtin_amdgcn_s_barrier();
    // ---- phase 1: MFMA(4-7 x 0-1); prefetch b[2-3]; stage (j+1,h3) ----
    __builtin_amdgcn_s_setprio(1);
    if (j < NT2 - 1) STAGE(j + 1, 3, nbuf);
    RDB(2, buf); RDB(3, buf);
    MM(4, 0); MM(4, 1); MM(5, 0); MM(5, 1);
    MM(6, 0); MM(6, 1); MM(7, 0); MM(7, 1);
    __builtin_amdgcn_s_setprio(0);
    __builtin_amdgcn_s_barrier();
    // ---- phase 2: MFMA(0-3 x 2-3); stage (j+2,h0)->buf ----
    // (buf A-reads all completed by ph1 consumption + ph1 barrier)
    __builtin_amdgcn_s_setprio(1);
    if (j < NT2 - 2) STAGE(j + 2, 0, buf);
    MM(0, 2); MM(0, 3); MM(1, 2); MM(1, 3);
    MM(2, 2); MM(2, 3); MM(3, 2); MM(3, 3);
    __builtin_amdgcn_s_setprio(0);
    __builtin_amdgcn_s_barrier();
    // ---- phase 3: stage (j+2,h1)->buf; drain tile j+1; MFMA(4-7 x 2-3);
    //      hoist next iteration's phase-0 reads (a[0-3],b[0-1] from nbuf) ----
    if (j < NT2 - 2) {
      STAGE(j + 2, 1, buf);
      asm volatile("s_waitcnt vmcnt(4)" ::: "memory");   // completes tile j+1
    } else if (j == NT2 - 2) {
      asm volatile("s_waitcnt vmcnt(0)" ::: "memory");
    }
    __builtin_amdgcn_s_barrier();
    __builtin_amdgcn_s_setprio(1);
    RDA(0, nbuf); RDA(1, nbuf); RDA(2, nbuf); RDA(3, nbuf);
    RDB(0, nbuf); RDB(1, nbuf);
    MM(4, 2); MM(4, 3); MM(5, 2); MM(5, 3);
    MM(6, 2); MM(6, 3); MM(7, 2); MM(7, 3);
    __builtin_amdgcn_s_setprio(0);
    __builtin_amdgcn_s_barrier();
  }

  // epilogue: C/D layout col=lane&15, row=(lane>>4)*4+jj
  const int crow = (lane >> 4) * 4;
  const int ccol = lane & 15;
#pragma unroll
  for (int m = 0; m < 8; ++m) {
#pragma unroll
    for (int n = 0; n < 4; ++n) {
#pragma unroll
      for (int jj = 0; jj < 4; ++jj) {
        int row = tileM + wm * 128 + m * 16 + crow + jj;
        int col = tileN + wn * 64 + n * 16 + ccol;
        C[(size_t)row * E_DIM + col] = f2bf(acc[m][n][jj]);
      }
    }
  }
#undef STAGE
#undef RDA
#undef RDB
#undef MM
}

// ---------------- blocked parallel scan ----------------
// P1: per (b,d,chunk) affine composition over CH2 steps.
// R8: 8 d's per thread, bf16x8 16B loads (coalescing sweet spot).
__global__ __launch_bounds__(256) void scan_p1_kernel(
    const unsigned short* __restrict__ ufr,
    unsigned short* __restrict__ Aout, unsigned short* __restrict__ Bout) {
  const int idx8 = blockIdx.x * 256 + threadIdx.x;  // (b, d/8): 2048 total
  const int s = blockIdx.y;
  const int b = idx8 >> 8;            // 256 d-groups per b
  const int d = (idx8 & 255) * 8;
  const unsigned short* up =
      ufr + ((size_t)(s * CH2) * B_DIM + b) * E_DIM + d;
  float Av[8], Bv[8];
#pragma unroll
  for (int q = 0; q < 8; ++q) { Av[q] = 1.f; Bv[q] = 0.f; }
#pragma unroll
  for (int it = 0; it < CH2; ++it) {
    u16x8 uv = *reinterpret_cast<const u16x8*>(up);
    u16x8 fv = *reinterpret_cast<const u16x8*>(up + D_DIM);
#pragma unroll
    for (int q = 0; q < 8; ++q) {
      float f = fast_sigmoid(bf2f(fv[q]));
      Av[q] *= f;
      Bv[q] = f * Bv[q] + (1.f - f) * bf2f(uv[q]);
    }
    up += (size_t)B_DIM * E_DIM;
  }
  size_t o = (size_t)s * BD + b * D_DIM + d;
  u16x8 ao, bo;
#pragma unroll
  for (int q = 0; q < 8; ++q) { ao[q] = f2bf(Av[q]); bo[q] = f2bf(Bv[q]); }
  *reinterpret_cast<u16x8*>(Aout + o) = ao;
  *reinterpret_cast<u16x8*>(Bout + o) = bo;
}

// P2: compose chunk boundaries sequentially.
// R8: batch-8 double-buffered prefetch hides the L2/L3 load latency of the
// serial 128-step chain. Named arrays + full unroll keep registers (rule #20).
__global__ __launch_bounds__(64) void scan_p2_kernel(
    const float* __restrict__ c0,
    const unsigned short* __restrict__ Ain, const unsigned short* __restrict__ Bin,
    unsigned short* __restrict__ cs, float* __restrict__ cT) {
  const int idx = blockIdx.x * 64 + threadIdx.x;
  float c = c0[idx];
  unsigned short aP[8], bP[8], aQ[8], bQ[8];
#define LOADB(AA, BB, sb)                                          \
  _Pragma("unroll")                                                \
  for (int q = 0; q < 8; ++q) {                                    \
    AA[q] = Ain[(size_t)((sb) + q) * BD + idx];                    \
    BB[q] = Bin[(size_t)((sb) + q) * BD + idx];                    \
  }
#define COMPB(AA, BB, sb)                                          \
  _Pragma("unroll")                                                \
  for (int q = 0; q < 8; ++q) {                                    \
    cs[(size_t)((sb) + q) * BD + idx] = f2bf(c);                   \
    c = bf2f(AA[q]) * c + bf2f(BB[q]);                             \
  }
  LOADB(aP, bP, 0);
  for (int sb = 0; sb < S2; sb += 16) {
    LOADB(aQ, bQ, sb + 8);
    COMPB(aP, bP, sb);
    if (sb + 16 < S2) { LOADB(aP, bP, sb + 16); }
    COMPB(aQ, bQ, sb + 8);
  }
#undef LOADB
#undef COMPB
  cT[idx] = c;
}

// P3 fused with GELU+LN: block = (b, chunk); 256 threads cover all D=2048.
// Re-runs CH2 steps from the chunk start state, then per-t block-LN, writes out.
// R6: x as bf16. R7: cs as bf16. R8: 16B loads. R9: tanh-form GELU (one
// v_exp via fast_tanh instead of libm erff; |err| vs exact < ~0.003,
// well inside the absmax margin 0.0625 vs 0.2275).
__global__ __launch_bounds__(256) void scan_p3ln_kernel(
    const unsigned short* __restrict__ xb,
    const unsigned short* __restrict__ ufr,
    const unsigned short* __restrict__ csb,
    const float* __restrict__ gamma,
    const float* __restrict__ beta,
    float* __restrict__ out) {
  const int b = blockIdx.x & (B_DIM - 1);
  const int s = blockIdx.x >> 3;
  const int tid = threadIdx.x;
  const int lane = tid & 63;
  const int wave = tid >> 6;
  const int d0 = tid * 8;
  __shared__ float red[8];

  float c[8];
  {
    u16x8 v = *reinterpret_cast<const u16x8*>(csb + (size_t)s * BD + b * D_DIM + d0);
#pragma unroll
    for (int q = 0; q < 8; ++q) c[q] = bf2f(v[q]);
  }
  float gam[8], bet[8];
  {
    float4 g0 = *(const float4*)(gamma + d0);
    float4 g1 = *(const float4*)(gamma + d0 + 4);
    float4 b0 = *(const float4*)(beta + d0);
    float4 b1 = *(const float4*)(beta + d0 + 4);
    gam[0]=g0.x; gam[1]=g0.y; gam[2]=g0.z; gam[3]=g0.w;
    gam[4]=g1.x; gam[5]=g1.y; gam[6]=g1.z; gam[7]=g1.w;
    bet[0]=b0.x; bet[1]=b0.y; bet[2]=b0.z; bet[3]=b0.w;
    bet[4]=b1.x; bet[5]=b1.y; bet[6]=b1.z; bet[7]=b1.w;
  }

  for (int it = 0; it < CH2; ++it) {
    const size_t rowo = (size_t)(s * CH2 + it) * B_DIM + b;
    const unsigned short* up = ufr + rowo * E_DIM + d0;
    u16x8 uv = *reinterpret_cast<const u16x8*>(up);
    u16x8 fv = *reinterpret_cast<const u16x8*>(up + D_DIM);
    u16x8 rv = *reinterpret_cast<const u16x8*>(up + 2 * D_DIM);
    u16x8 xv = *reinterpret_cast<const u16x8*>(xb + rowo * D_DIM + d0);

    float g[8];
    float s1 = 0.f, sq = 0.f;
#pragma unroll
    for (int jj = 0; jj < 8; ++jj) {
      float f = fast_sigmoid(bf2f(fv[jj]));
      float r = fast_sigmoid(bf2f(rv[jj]));
      c[jj] = f * c[jj] + (1.f - f) * bf2f(uv[jj]);
      float h = r * fast_tanh(c[jj]) + (1.f - r) * bf2f(xv[jj]);
      float t = fast_tanh(0.79788456f * (h + 0.044715f * h * h * h));
      float gg = 0.5f * h * (1.f + t);
      g[jj] = gg;
      s1 += gg;
      sq += gg * gg;
    }
#pragma unroll
    for (int off = 32; off; off >>= 1) {
      s1 += __shfl_xor(s1, off);
      sq += __shfl_xor(sq, off);
    }
    if (lane == 0) { red[wave] = s1; red[4 + wave] = sq; }
    __syncthreads();
    float S1 = red[0] + red[1] + red[2] + red[3];
    float Sq = red[4] + red[5] + red[6] + red[7];
    __syncthreads();  // red reused next iteration
    float mean = S1 * (1.f / D_DIM);
    float var  = Sq * (1.f / D_DIM) - mean * mean;
    float inv = rsqrtf(var + LN_EPS);

    float* op = out + rowo * D_DIM + d0;
    float4 o0 = {(g[0] - mean) * inv * gam[0] + bet[0],
                 (g[1] - mean) * inv * gam[1] + bet[1],
                 (g[2] - mean) * inv * gam[2] + bet[2],
                 (g[3] - mean) * inv * gam[3] + bet[3]};
    float4 o1 = {(g[4] - mean) * inv * gam[4] + bet[4],
                 (g[5] - mean) * inv * gam[5] + bet[5],
                 (g[6] - mean) * inv * gam[6] + bet[6],
                 (g[7] - mean) * inv * gam[7] + bet[7]};
    *(float4*)op = o0;
    *(float4*)(op + 4) = o1;
  }
}

extern "C" void kernel_launch(void* const* d_in, const int* in_sizes, int n_in,
                              void* d_out, int out_size, void* d_ws, size_t ws_size,
                              hipStream_t stream) {
  const float* x     = (const float*)d_in[0];
  const float* c0    = (const float*)d_in[1];
  const float* W     = (const float*)d_in[2];
  const float* gamma = (const float*)d_in[3];
  const float* beta  = (const float*)d_in[4];
  float* out = (float*)d_out;
  float* cT  = out + (size_t)N_ROWS * D_DIM;

  unsigned short* ufr = (unsigned short*)d_ws;                 // [N_ROWS][E] bf16
  unsigned short* xb  = ufr + (size_t)N_ROWS * E_DIM;          // [N_ROWS][K] bf16
  unsigned short* wb  = xb + (size_t)N_ROWS * K_DIM;           // [E][K] bf16

  // scan scratch reuses wb region (dead after gemm; xb stays live for p3):
  // 3 * S2*BD*2 = 12.6MB < 25.2MB (wb size). All bf16.
  unsigned short* Abuf = wb;
  unsigned short* Bbuf = Abuf + (size_t)S2 * BD;
  unsigned short* csb  = Bbuf + (size_t)S2 * BD;

  int nx8 = N_ROWS * K_DIM / 8;
  int nw8 = E_DIM * K_DIM / 8;
  cvt2_kernel<<<(nx8 + nw8 + 255) / 256, 256, 0, stream>>>(x, xb, nx8, W, wb, nw8);

  (void)hipFuncSetAttribute((const void*)gemm8_kernel,
                            hipFuncAttributeMaxDynamicSharedMemorySize, 131072);
  gemm8_kernel<<<768, 512, 131072, stream>>>(xb, wb, ufr);

  dim3 sg(BD / 8 / 256, S2);  // (8, 128)
  scan_p1_kernel<<<sg, 256, 0, stream>>>(ufr, Abuf, Bbuf);
  scan_p2_kernel<<<BD / 64, 64, 0, stream>>>(c0, Abuf, Bbuf, csb, cT);
  scan_p3ln_kernel<<<B_DIM * S2, 256, 0, stream>>>(xb, ufr, csb, gamma, beta, out);
}